// Round 1
// 306.918 us; speedup vs baseline: 1.0019x; 1.0019x over previous
//
#include <hip/hip_runtime.h>

// ---------------------------------------------------------------------------
// Types & helpers
// ---------------------------------------------------------------------------
typedef __attribute__((ext_vector_type(8))) short bf16x8;
typedef __attribute__((ext_vector_type(4))) float f32x4;

__device__ __forceinline__ short f2bf(float f) {
  union { float f; unsigned u; } a; a.f = f;
  unsigned r = a.u + 0x7fffu + ((a.u >> 16) & 1u);   // RNE
  return (short)(r >> 16);
}
__device__ __forceinline__ float bf2f(short s) {
  union { unsigned u; float f; } a;
  a.u = ((unsigned)(unsigned short)s) << 16; return a.f;
}
__device__ __forceinline__ float blo(unsigned u) { union { unsigned u; float f; } a; a.u = u << 16; return a.f; }
__device__ __forceinline__ float bhi(unsigned u) { union { unsigned u; float f; } a; a.u = u & 0xffff0000u; return a.f; }
__device__ __forceinline__ unsigned packbf(float lo, float hi) {
  return (unsigned)(unsigned short)f2bf(lo) | ((unsigned)(unsigned short)f2bf(hi) << 16);
}
__device__ __forceinline__ void ldscp16(const void* g, void* l) {
  __builtin_amdgcn_global_load_lds((const __attribute__((address_space(1))) void*)g,
                                   (__attribute__((address_space(3))) void*)l, 16, 0, 0);
}
__device__ __forceinline__ void stv(float* p, float v) { *p = v; }
__device__ __forceinline__ void stv(short* p, float v) { *p = f2bf(v); }

// ---------------------------------------------------------------------------
// Merged setup. Blocks:
//  [0,8192)      cvt_w: slots 0 qs^T_g,1 ks^T_g,2 vs^T_g,3 ps,4 qt^T_g,
//                5 kt^T_g,6 vt^T_g,7 pt  (q/k/v transposed [c_in][c_out],
//                gamma folded on c_in; needed by the fold GEMMs)
//  [8192,8512)   zero 320 KB (ss_s|ss_t|rsum|us|ut)
//  [8512,9024)   row-folds, 4 waves/block, row b = (bid-8512)*4+wave:
//     b<512   : bt_s[b]   = ps_w[b,:].vs_b + ps_b[b]
//     b<1024  : bt_t[...] = pt_w.vt_b + pt_b
//     b<1536  : wus[c]    = g_s[c] * sum_o ks_w[o][c]*qs_b[o]   (u-vector wt)
//     b<2048  : wut[c]    = g_t[c] * sum_o kt_w[o][c]*qt_b[o]
// ---------------------------------------------------------------------------
__global__ __launch_bounds__(256) void setup_all(
    const float* __restrict__ w0, const float* __restrict__ w1,
    const float* __restrict__ w2, const float* __restrict__ w3,
    const float* __restrict__ w4, const float* __restrict__ w5,
    const float* __restrict__ w6, const float* __restrict__ w7,
    const float* __restrict__ g_s, const float* __restrict__ g_t,
    short* __restrict__ Wb, float* __restrict__ zs,
    const float* __restrict__ qs_b, const float* __restrict__ vs_b,
    const float* __restrict__ ps_b, const float* __restrict__ qt_b,
    const float* __restrict__ vt_b, const float* __restrict__ pt_b,
    float* __restrict__ bt_s, float* __restrict__ bt_t,
    float* __restrict__ wus, float* __restrict__ wut) {
  const int bid = blockIdx.x, tid = threadIdx.x;
  if (bid < 8192) {                                  // ---- cvt_w ----
    int idx = bid * 256 + tid;
    const float* ws[8] = {w0, w1, w2, w3, w4, w5, w6, w7};
    int wi = idx >> 18, loc = idx & 262143;
    int r = loc >> 9, q = loc & 511;
    float v, g;
    if (wi == 3 || wi == 7) { v = ws[wi][loc]; g = 1.f; }
    else {                                           // transposed, gamma on c_in=r
      v = ws[wi][q * 512 + r];
      g = (wi <= 2) ? g_s[r] : g_t[r];
    }
    Wb[idx] = f2bf(v * g);
  } else if (bid < 8512) {                           // ---- zero 320 KB ----
    zs[(bid - 8192) * 256 + tid] = 0.f;
  } else {                                           // ---- row folds ----
    const int w = tid >> 6, lane = tid & 63;
    const int b = (bid - 8512) * 4 + w;              // [0,2048)
    float s = 0.f;
    if (b < 1024) {                                  // bt = p_w.v_b + p_b
      const bool sp = b < 512;
      const float* W = sp ? w3 : w7;                 // ps_w : pt_w
      const float* vb = sp ? vs_b : vt_b;
      const int r = b & 511;
#pragma unroll
      for (int c = lane; c < 512; c += 64) s += W[r * 512 + c] * vb[c];
#pragma unroll
      for (int off = 32; off > 0; off >>= 1) s += __shfl_xor(s, off);
      if (lane == 0) (sp ? bt_s : bt_t)[r] = s + (sp ? ps_b : pt_b)[r];
    } else {                                         // wu = g * K_w^T.q_b
      const bool sp = b < 1536;
      const float* W = sp ? w1 : w5;                 // ks_w : kt_w
      const float* qb = sp ? qs_b : qt_b;
      const int c = b & 511;
#pragma unroll
      for (int o = lane; o < 512; o += 64) s += W[o * 512 + c] * qb[o];
#pragma unroll
      for (int off = 32; off > 0; off >>= 1) s += __shfl_xor(s, off);
      if (lane == 0)
        (sp ? wus : wut)[c] = s * (sp ? g_s[c] : g_t[c]);
    }
  }
}

// ---------------------------------------------------------------------------
// Transpose + sum-of-squares + u-dot (spatial). src [512][16384] fp32 ->
// dst [16384][512] bf16 (x^T), xb [512][16384] bf16 (straight cast),
// ss[n] += sum_c src[c][n]^2 ; us[n] += sum_c wu[c]*src[c][n].
// ---------------------------------------------------------------------------
__global__ __launch_bounds__(256) void txp_sumsq(
    const float* __restrict__ src, short* __restrict__ dst,
    short* __restrict__ xb, float* __restrict__ ss,
    const float* __restrict__ wu, float* __restrict__ us) {
  constexpr long N = 16384;
  __shared__ short T[64][66];
  __shared__ float part[16][16][4];
  __shared__ float part2[16][16][4];
  const int tid = threadIdx.x;
  const long n0 = (long)blockIdx.x * 64;
  const int c0 = blockIdx.y * 64;
  const int n4 = (tid & 15) * 4;
  float s0 = 0.f, s1 = 0.f, s2 = 0.f, s3 = 0.f;
  float u0 = 0.f, u1 = 0.f, u2 = 0.f, u3 = 0.f;
#pragma unroll
  for (int i = 0; i < 4; ++i) {
    int cl = i * 16 + (tid >> 4);
    float4 v = *(const float4*)&src[(long)(c0 + cl) * N + n0 + n4];
    float wc = wu[c0 + cl];
    s0 += v.x * v.x; s1 += v.y * v.y; s2 += v.z * v.z; s3 += v.w * v.w;
    u0 += wc * v.x; u1 += wc * v.y; u2 += wc * v.z; u3 += wc * v.w;
    short e0 = f2bf(v.x), e1 = f2bf(v.y), e2 = f2bf(v.z), e3 = f2bf(v.w);
    T[n4 + 0][cl] = e0; T[n4 + 1][cl] = e1;
    T[n4 + 2][cl] = e2; T[n4 + 3][cl] = e3;
    uint2 o;
    o.x = (unsigned)(unsigned short)e0 | ((unsigned)(unsigned short)e1 << 16);
    o.y = (unsigned)(unsigned short)e2 | ((unsigned)(unsigned short)e3 << 16);
    *(uint2*)&xb[(long)(c0 + cl) * N + n0 + n4] = o;
  }
  part[tid >> 4][tid & 15][0] = s0; part[tid >> 4][tid & 15][1] = s1;
  part[tid >> 4][tid & 15][2] = s2; part[tid >> 4][tid & 15][3] = s3;
  part2[tid >> 4][tid & 15][0] = u0; part2[tid >> 4][tid & 15][1] = u1;
  part2[tid >> 4][tid & 15][2] = u2; part2[tid >> 4][tid & 15][3] = u3;
  __syncthreads();
  if (tid < 64) {
    float s = 0.f, u = 0.f;
#pragma unroll
    for (int cg = 0; cg < 16; ++cg) {
      s += part[cg][tid >> 2][tid & 3];
      u += part2[cg][tid >> 2][tid & 3];
    }
    atomicAdd(&ss[n0 + tid], s);
    atomicAdd(&us[n0 + tid], u);
  }
#pragma unroll
  for (int p = 0; p < 4; ++p) {
    int nl = p * 16 + (tid >> 4);
    int cl = (tid & 15) * 4;
    uint2 o;
    o.x = (unsigned)(unsigned short)T[nl][cl] |
          ((unsigned)(unsigned short)T[nl][cl + 1] << 16);
    o.y = (unsigned)(unsigned short)T[nl][cl + 2] |
          ((unsigned)(unsigned short)T[nl][cl + 3] << 16);
    *(uint2*)&dst[(n0 + nl) * 512 + c0 + cl] = o;
  }
}

// ---------------------------------------------------------------------------
// Generic NT GEMM: D[i,j] = f( scale * sum_k A[i,k]*B[j,k] ) (+bias,+resid)
// SCALE_MODE: 0 none; 1 row-rms; 2 col-rms; 3 row-recip (softmax denom);
//             4 QK-fold+EXP: val = exp(scale*csc*(rms_row*acc + uvec[col])),
//               rowsum(atomic->rs) of unscaled exp, store val*csc.
// RESID_MODE: 0 none; 1 fp32 same-layout; 2 bf16 same-layout;
//             3 bf16 transposed (residb[j*512+i], uint2-gathered)
// EPI: 0 none; 1 EXP-rowsum (with SCALE4); 3 SUMSQ->rs + dot(wvec)->rs2
// FOLD: z indexes slot tables A{3,7,0,4} B{2,6,1,5} in Wb (weight folds).
//
// T3 2-phase pipeline (this round's change): LDS double-buffered; tile k+1's
// global_load_lds batch is ISSUED before tile k's ds_read+MFMA, and the
// single __syncthreads() (implicit vmcnt(0)+lgkmcnt(0) drain) sits at the
// END of the K-step — the load latency drains under the MFMA phase instead
// of serializing after it. BM=128/BK=64 dbuf = 64 KB LDS -> 2 blocks/CU
// (8 waves). BK=128 would be 128 KB -> 1 block/CU (m132 trap), so all
// call sites use BK=64 now.
// xor-swizzled LDS (chunk-xor by row & (BK/8-1)): 2-way max, free (m136).
// ---------------------------------------------------------------------------
template <typename OutT, int BIAS_MODE, int SCALE_MODE, int RESID_MODE, int EPI,
          int BM = 128, int FOLD = 0, int BK = 64>
__global__ __launch_bounds__(256, 2) void gemm_nt(
    const short* __restrict__ A, const short* __restrict__ B,
    OutT* __restrict__ D, const float* __restrict__ bias,
    const float* __restrict__ ssv, const float* __restrict__ uvec,
    float* __restrict__ rs, float* __restrict__ rs2,
    const float* __restrict__ wvec,
    const float* __restrict__ residf, const short* __restrict__ residb,
    int K, int lda, int ldb, int ldd,
    long aBatch, long bBatch, long dBatch, long sBatch, float scale) {
  constexpr int WR = BM / 64;                        // wave rows
  constexpr int WC = 4 / WR;                         // wave cols
  constexpr int NW = (128 / WC) / 16;                // B-frags per wave (4 or 8)
  constexpr int CH = BK / 8;                         // 16B chunks per row (8/16)
  constexpr int MSK = CH - 1;
  constexpr int RPR = 256 / CH;                      // rows staged per round
  constexpr int ASZ = BM * BK;                       // elements per buffer
  constexpr int BSZ = 128 * BK;
  __shared__ short As[2 * ASZ];
  __shared__ short Bs[2 * BSZ];
  const int tid = threadIdx.x;
  const int bz = blockIdx.z;
  const long i0 = (long)blockIdx.x * BM;
  const long j0 = (long)blockIdx.y * 128;
  long aOff, bOff;
  if (FOLD) {
    aOff = 262144L * (bz < 2 ? 3 + 4 * bz : 4 * (bz - 2));
    bOff = 262144L * (bz < 2 ? 2 + 4 * bz : 1 + 4 * (bz - 2));
  } else {
    aOff = bz * aBatch; bOff = bz * bBatch;
  }
  const short* Ab = A + aOff + i0 * lda;
  const short* Bb = B + bOff + j0 * ldb;
  const int srow = tid / CH, scol = tid & MSK;
  const int lane = tid & 63;
  const int waveid = tid >> 6;
  const int wr = (waveid / WC) * 64;
  const int wc = (waveid % WC) * 64;
  const int quad = lane >> 4, l15 = lane & 15;

  f32x4 acc[4][NW] = {};

  // stage tile (k0) into buffer buf (async; completion = vmcnt drain @barrier)
  auto stage = [&](int buf, int k0) {
#pragma unroll
    for (int p = 0; p < BM / RPR; ++p) {
      int row = p * RPR + srow;
      int gc = (scol ^ (row & MSK)) << 3;
      ldscp16(Ab + (long)row * lda + k0 + gc,
              &As[buf * ASZ + p * 2048 + tid * 8]);
    }
#pragma unroll
    for (int p = 0; p < 128 / RPR; ++p) {
      int row = p * RPR + srow;
      int gc = (scol ^ (row & MSK)) << 3;
      ldscp16(Bb + (long)row * ldb + k0 + gc,
              &Bs[buf * BSZ + p * 2048 + tid * 8]);
    }
  };

  stage(0, 0);                                       // prologue
  __syncthreads();                                   // tile 0 resident

  int cur = 0;
  for (int k0 = 0; k0 < K; k0 += BK) {
    if (k0 + BK < K) stage(cur ^ 1, k0 + BK);        // issue next tile FIRST
    const short* Ar = &As[cur * ASZ];
    const short* Br = &Bs[cur * BSZ];
#pragma unroll
    for (int kk = 0; kk < BK / 32; ++kk) {
      bf16x8 af[4], bfr[NW];
#pragma unroll
      for (int a = 0; a < 4; ++a) {
        int row = wr + a * 16 + l15;
        int g = kk * 4 + quad;
        af[a] = *(const bf16x8*)&Ar[row * BK + ((g ^ (row & MSK)) << 3)];
      }
#pragma unroll
      for (int b = 0; b < NW; ++b) {
        int row = wc + b * 16 + l15;
        int g = kk * 4 + quad;
        bfr[b] = *(const bf16x8*)&Br[row * BK + ((g ^ (row & MSK)) << 3)];
      }
#pragma unroll
      for (int a = 0; a < 4; ++a)
#pragma unroll
        for (int b = 0; b < NW; ++b)
          acc[a][b] = __builtin_amdgcn_mfma_f32_16x16x32_bf16(af[a], bfr[b], acc[a][b], 0, 0, 0);
    }
    __syncthreads();                                 // drain next-tile loads under
    cur ^= 1;                                        // the MFMAs above
  }

  const long Doff = bz * dBatch;
#pragma unroll
  for (int a = 0; a < 4; ++a) {
    const int rb = (int)i0 + wr + a * 16 + quad * 4;   // C/D: row = quad*4+reg
    float rsc[4];
    if (SCALE_MODE == 1 || SCALE_MODE == 4) {
#pragma unroll
      for (int r = 0; r < 4; ++r)
        rsc[r] = 22.627416997969522f /
                 fmaxf(sqrtf(ssv[bz * sBatch + rb + r]), 1e-12f);
    }
    if (SCALE_MODE == 3) {
#pragma unroll
      for (int r = 0; r < 4; ++r)
        rsc[r] = 1.f / ssv[bz * sBatch + rb + r];
    }
    float rp1[4] = {0.f, 0.f, 0.f, 0.f};
    float rp2[4] = {0.f, 0.f, 0.f, 0.f};
#pragma unroll
    for (int b = 0; b < NW; ++b) {
      const int cc = (int)j0 + wc + b * 16 + l15;      // C/D: col = lane&15
      float csc = 1.f, uu = 0.f, wv = 0.f;
      if (SCALE_MODE == 2 || SCALE_MODE == 4)
        csc = 22.627416997969522f /
              fmaxf(sqrtf(ssv[bz * sBatch + cc]), 1e-12f);
      if (SCALE_MODE == 4) uu = uvec[bz * sBatch + cc];
      if (EPI == 3) wv = wvec[cc];
      uint2 rtv;
      if (RESID_MODE == 3)
        rtv = *(const uint2*)&residb[(long)cc * 512 + rb];
#pragma unroll
      for (int r = 0; r < 4; ++r) {
        float val;
        if (SCALE_MODE == 4) {
          val = __expf(scale * csc * (rsc[r] * acc[a][b][r] + uu));
          rp1[r] += val;
          val *= csc;
        } else {
          val = acc[a][b][r] * scale;
          if (SCALE_MODE == 1 || SCALE_MODE == 3) val *= rsc[r];
          if (SCALE_MODE == 2) val *= csc;
        }
        if (BIAS_MODE == 1) val += bias[rb + r];
        if (BIAS_MODE == 2) val += bias[cc];
        const long off = Doff + (long)(rb + r) * ldd + cc;
        if (RESID_MODE == 1) val += residf[off];
        if (RESID_MODE == 2) val += bf2f(residb[off]);
        if (RESID_MODE == 3) val += bf2f(((const short*)&rtv)[r]);
        stv(D + off, val);
        if (EPI == 3) { rp1[r] += val * val; rp2[r] += val * wv; }
      }
    }
    if (EPI == 1 || EPI == 3) {
#pragma unroll
      for (int r = 0; r < 4; ++r) {
        float s = rp1[r];
#pragma unroll
        for (int off = 1; off < 16; off <<= 1) s += __shfl_xor(s, off);
        if (l15 == 0) atomicAdd(&rs[bz * sBatch + rb + r], s);
      }
      if (EPI == 3) {
#pragma unroll
        for (int r = 0; r < 4; ++r) {
          float s = rp2[r];
#pragma unroll
          for (int off = 1; off < 16; off <<= 1) s += __shfl_xor(s, off);
          if (l15 == 0) atomicAdd(&rs2[bz * sBatch + rb + r], s);
        }
      }
    }
  }
}

// ---------------------------------------------------------------------------
// Temporal attention v5 — QK-folded. h2: [16384][512] bf16, Tt = Mt.h2
// [16384][512] bf16. S[i,j] = scale*(rms_i*rms_j*(h2_i.Tt_j) + rms_j*ut_j).
// Block per pixel; V = rms-folded h2 (V projection folded into out-GEMM).
// ---------------------------------------------------------------------------
__global__ __launch_bounds__(256) void temporal_attn_v5(
    const short* __restrict__ h2, const short* __restrict__ Tt,
    const float* __restrict__ ss, const float* __restrict__ ut,
    const int* __restrict__ wndp, short* __restrict__ o, float scale) {
  constexpr int RS = 520;                            // 512 + 8 pad
  __shared__ short hq[16 * RS];
  __shared__ short tk[16 * RS];
  __shared__ float Plds[16][17];
  const int tid = threadIdx.x;
  const int w = tid >> 6, lane = tid & 63;
  const int hw = blockIdx.x;
  const int wnd = *wndp;

#pragma unroll
  for (int i = 0; i < 8; ++i) {
    int ci = w * 8 + i;                              // 32 rows: 0..15 h2, 16..31 Tt
    int t = ci & 15;
    const short* src = (ci < 16) ? h2 : Tt;
    short* dst = (ci < 16) ? hq : tk;
    ldscp16(src + (long)(t * 1024 + hw) * 512 + lane * 8,
            dst + t * RS + lane * 8);
  }
  const int c0 = lane * 8;
  uint4 vch[16];
#pragma unroll
  for (int tp = 0; tp < 16; ++tp)
    vch[tp] = *(const uint4*)(h2 + (long)(tp * 1024 + hw) * 512 + c0);
  __syncthreads();

  if (w == 0) {
    const int quad = lane >> 4, m = lane & 15;
    f32x4 sacc = {};
#pragma unroll
    for (int s = 0; s < 16; ++s) {
      bf16x8 aq = *(const bf16x8*)&hq[m * RS + quad * 8 + s * 32];
      bf16x8 bk = *(const bf16x8*)&tk[m * RS + quad * 8 + s * 32];
      sacc = __builtin_amdgcn_mfma_f32_16x16x32_bf16(aq, bk, sacc, 0, 0, 0);
    }
    const float rmsj = 22.627416997969522f /
                       fmaxf(sqrtf(ss[m * 1024 + hw]), 1e-12f);
    const float uj = ut[m * 1024 + hw];
#pragma unroll
    for (int r = 0; r < 4; ++r) {
      const int i = quad * 4 + r;
      const int j = m;
      const float rmsi = 22.627416997969522f /
                         fmaxf(sqrtf(ss[i * 1024 + hw]), 1e-12f);
      const bool allowed = (j <= i) && (wnd <= 0 || (i - j) < wnd);
      float val = allowed ? scale * (rmsi * rmsj * sacc[r] + rmsj * uj) : -1e30f;
      float mx = val;
#pragma unroll
      for (int off = 1; off < 16; off <<= 1) mx = fmaxf(mx, __shfl_xor(mx, off));
      float e = allowed ? __expf(val - mx) : 0.f;
      float sum = e;
#pragma unroll
      for (int off = 1; off < 16; off <<= 1) sum += __shfl_xor(sum, off);
      Plds[i][j] = (e / sum) * rmsj;                 // rms_j folded into P (V-fold)
    }
  }
  __syncthreads();

#pragma unroll
  for (int r = 0; r < 4; ++r) {
    const int t = w * 4 + r;
    const int tlo = (wnd > 0 && t - wnd + 1 > 0) ? t - wnd + 1 : 0;
    float a0 = 0.f, a1 = 0.f, a2 = 0.f, a3 = 0.f,
          a4 = 0.f, a5 = 0.f, a6 = 0.f, a7 = 0.f;
#pragma unroll
    for (int tp = 0; tp < 16; ++tp) {
      const float p = (tp >= tlo && tp <= t) ? Plds[t][tp] : 0.f;
      const uint4 vv = vch[tp];
      a0 += p * blo(vv.x); a1 += p * bhi(vv.x);
      a2 += p * blo(vv.y); a3 += p * bhi(vv.y);
      a4 += p * blo(vv.z); a5 += p * bhi(vv.z);
      a6 += p * blo(vv.w); a7 += p * bhi(vv.w);
    }
    uint4 ov;
    ov.x = packbf(a0, a1); ov.y = packbf(a2, a3);
    ov.z = packbf(a4, a5); ov.w = packbf(a6, a7);
    *(uint4*)(o + (long)(t * 1024 + hw) * 512 + c0) = ov;
  }
}

// ---------------------------------------------------------------------------
// Launch
// ---------------------------------------------------------------------------
extern "C" void kernel_launch(void* const* d_in, const int* in_sizes, int n_in,
                              void* d_out, int out_size, void* d_ws, size_t ws_size,
                              hipStream_t stream) {
  const float* x    = (const float*)d_in[0];
  const float* qs_w = (const float*)d_in[1];
  const float* qs_b = (const float*)d_in[2];
  const float* ks_w = (const float*)d_in[3];
  const float* ks_b = (const float*)d_in[4];
  const float* vs_w = (const float*)d_in[5];
  const float* vs_b = (const float*)d_in[6];
  const float* ps_w = (const float*)d_in[7];
  const float* ps_b = (const float*)d_in[8];
  const float* qt_w = (const float*)d_in[9];
  const float* qt_b = (const float*)d_in[10];
  const float* kt_w = (const float*)d_in[11];
  const float* kt_b = (const float*)d_in[12];
  const float* vt_w = (const float*)d_in[13];
  const float* vt_b = (const float*)d_in[14];
  const float* pt_w = (const float*)d_in[15];
  const float* pt_b = (const float*)d_in[16];
  const float* g_s  = (const float*)d_in[17];
  const float* g_t  = (const float*)d_in[18];
  const int*   wnd  = (const int*)d_in[19];
  float* out = (float*)d_out;
  (void)ks_b; (void)kt_b;   // K biases appear only via wu (zero cross-terms cancel)

  // workspace carve (~136 MB)
  char* w = (char*)d_ws;
  short* Wb   = (short*)(w);                               // 4 MB: 8 weight slots
  float* ss_s = (float*)(w + (4L << 20));                  // 64 KB (zeroed group start)
  float* ss_t = (float*)(w + (4L << 20) + (64 << 10));     // 64 KB
  float* rsum = (float*)(w + (4L << 20) + (128 << 10));    // 64 KB
  float* us   = (float*)(w + (4L << 20) + (192 << 10));    // 64 KB
  float* ut   = (float*)(w + (4L << 20) + (256 << 10));    // 64 KB (zeroed group end)
  float* bt_s = (float*)(w + (4L << 20) + (320 << 10));    // 2 KB folded bias
  float* bt_t = (float*)(w + (4L << 20) + (324 << 10));    // 2 KB
  float* wus  = (float*)(w + (4L << 20) + (328 << 10));    // 2 KB u-weights
  float* wut  = (float*)(w + (4L << 20) + (332 << 10));    // 2 KB
  short* WF   = (short*)(w + (4L << 20) + (512 << 10));    // 2 MB: Wpv_s|Wpv_t|Mqk_s|Mqk_t
  short* Wpv  = WF;
  short* Mqk  = WF + 2 * 262144;
  short* hb   = (short*)(w + (8L << 20));                  // 16 MB: [16384][512] bf16 x^T
  short* Tb   = (short*)(w + (24L << 20));                 // 16 MB: [16384][512] T = M.h
  short* xb   = (short*)(w + (40L << 20));                 // 16 MB: [512][16384] bf16 x
  short* oT   = (short*)(w + (56L << 20));                 // 16 MB: [16384][512] h~
  short* h2   = (short*)(w + (72L << 20));                 // 16 MB: [16384][512]
  short* S    = (short*)(w + (88L << 20));                 // 32 MB: [16][1024][1024]
  (void)in_sizes; (void)n_in; (void)out_size; (void)ws_size;

  const float scale = 0.04419417382415922f;                // 512^-0.5

  setup_all<<<9024, 256, 0, stream>>>(
      qs_w, ks_w, vs_w, ps_w, qt_w, kt_w, vt_w, pt_w, g_s, g_t, Wb, ss_s,
      qs_b, vs_b, ps_b, qt_b, vt_b, pt_b, bt_s, bt_t, wus, wut);
  // Merged weight folds (z slot tables): z0 Wpv_s=ps.vs_g, z1 Wpv_t=pt.vt_g,
  // z2 Mqk_s=qs_g^T.ks_g, z3 Mqk_t=qt_g^T.kt_g
  gemm_nt<short, 0, 0, 0, 0, 128, 1><<<dim3(4, 4, 4), 256, 0, stream>>>(
      Wb, Wb, WF, nullptr, nullptr, nullptr, nullptr, nullptr, nullptr,
      nullptr, nullptr, 512, 512, 512, 512, 0, 0, 262144L, 0, 1.f);

  // ---------------- spatial ----------------
  txp_sumsq<<<dim3(256, 8, 1), 256, 0, stream>>>(x, hb, xb, ss_s, wus, us);
  // T[n][a] = hb[n,:] . Mqk_s[a,:]
  gemm_nt<short, 0, 0, 0, 0, 128><<<dim3(128, 4, 1), 256, 0, stream>>>(
      hb, Mqk, Tb, nullptr, nullptr, nullptr, nullptr, nullptr, nullptr,
      nullptr, nullptr, 512, 512, 512, 512, 0, 0, 0, 0, 1.f);
  // expS'[t][l][m] = exp(scale*rms_m*(rms_l*(hb_l.T_m)+us_m))*rms_m ; rsum+=
  // BM=128 dbuf pipelined (was BM=256 serial)
  gemm_nt<short, 0, 4, 0, 1, 128><<<dim3(8, 8, 16), 256, 0, stream>>>(
      hb, Tb, S, nullptr, ss_s, us, rsum, nullptr, nullptr, nullptr, nullptr,
      512, 512, 512, 1024,
      1024L * 512, 1024L * 512, 1024L * 1024, 1024, scale);
  // h~[n][c] = (1/rsum) * sum_m expS'[l,m] * xb[c,m]
  gemm_nt<short, 0, 3, 0, 0, 128><<<dim3(8, 4, 16), 256, 0, stream>>>(
      S, xb, oT, nullptr, rsum, nullptr, nullptr, nullptr, nullptr,
      nullptr, nullptr, 1024, 1024, 16384, 512,
      1024L * 1024, 1024L, 1024L * 512, 1024, 1.f);
  // h2[n][c] = bf16( hb[n][c] + bt_s[c] + (oT.Wpv_s^T)[n][c] );
  //   ss_t += val^2 ; ut += val*wut[c]
  gemm_nt<short, 2, 0, 2, 3, 128><<<dim3(128, 4, 1), 256, 0, stream>>>(
      oT, Wpv, h2, bt_s, nullptr, nullptr, ss_t, ut, wut, nullptr, hb,
      512, 512, 512, 512, 0, 0, 0, 1024, 1.f);

  // ---------------- temporal ----------------
  // Tt[n][a] = h2[n,:] . Mqk_t[a,:]
  gemm_nt<short, 0, 0, 0, 0, 128><<<dim3(128, 4, 1), 256, 0, stream>>>(
      h2, Mqk + 262144, Tb, nullptr, nullptr, nullptr, nullptr, nullptr,
      nullptr, nullptr, nullptr, 512, 512, 512, 512, 0, 0, 0, 0, 1.f);
  temporal_attn_v5<<<1024, 256, 0, stream>>>(h2, Tb, ss_t, ut, wnd, oT, scale);
  // out[c,n] = h2[n][c] + bt_t[c] + Wpv_t[c,:] . h~[n,:]   (fp32, c-major)
  gemm_nt<float, 1, 0, 3, 0, 128><<<dim3(4, 128, 1), 256, 0, stream>>>(
      Wpv + 262144, oT, out, bt_t, nullptr, nullptr, nullptr, nullptr,
      nullptr, nullptr, h2, 512, 512, 512, 16384, 0, 0, 0, 0, 1.f);
}

// Round 2
// 305.467 us; speedup vs baseline: 1.0067x; 1.0048x over previous
//
#include <hip/hip_runtime.h>

// ---------------------------------------------------------------------------
// Types & helpers
// ---------------------------------------------------------------------------
typedef __attribute__((ext_vector_type(8))) short bf16x8;
typedef __attribute__((ext_vector_type(4))) float f32x4;

__device__ __forceinline__ short f2bf(float f) {
  union { float f; unsigned u; } a; a.f = f;
  unsigned r = a.u + 0x7fffu + ((a.u >> 16) & 1u);   // RNE
  return (short)(r >> 16);
}
__device__ __forceinline__ float bf2f(short s) {
  union { unsigned u; float f; } a;
  a.u = ((unsigned)(unsigned short)s) << 16; return a.f;
}
__device__ __forceinline__ float blo(unsigned u) { union { unsigned u; float f; } a; a.u = u << 16; return a.f; }
__device__ __forceinline__ float bhi(unsigned u) { union { unsigned u; float f; } a; a.u = u & 0xffff0000u; return a.f; }
__device__ __forceinline__ unsigned packbf(float lo, float hi) {
  return (unsigned)(unsigned short)f2bf(lo) | ((unsigned)(unsigned short)f2bf(hi) << 16);
}
__device__ __forceinline__ void ldscp16(const void* g, void* l) {
  __builtin_amdgcn_global_load_lds((const __attribute__((address_space(1))) void*)g,
                                   (__attribute__((address_space(3))) void*)l, 16, 0, 0);
}
__device__ __forceinline__ void stv(float* p, float v) { *p = v; }
__device__ __forceinline__ void stv(short* p, float v) { *p = f2bf(v); }

// ---------------------------------------------------------------------------
// Merged setup. Blocks:
//  [0,8192)      cvt_w: slots 0 qs^T_g,1 ks^T_g,2 vs^T_g,3 ps,4 qt^T_g,
//                5 kt^T_g,6 vt^T_g,7 pt  (q/k/v transposed [c_in][c_out],
//                gamma folded on c_in; needed by the fold GEMMs)
//  [8192,8512)   zero 320 KB (ss_s|ss_t|rsum|us|ut)
//  [8512,9024)   row-folds, 4 waves/block, row b = (bid-8512)*4+wave:
//     b<512   : bt_s[b]   = ps_w[b,:].vs_b + ps_b[b]
//     b<1024  : bt_t[...] = pt_w.vt_b + pt_b
//     b<1536  : wus[c]    = g_s[c] * sum_o ks_w[o][c]*qs_b[o]   (u-vector wt)
//     b<2048  : wut[c]    = g_t[c] * sum_o kt_w[o][c]*qt_b[o]
// ---------------------------------------------------------------------------
__global__ __launch_bounds__(256) void setup_all(
    const float* __restrict__ w0, const float* __restrict__ w1,
    const float* __restrict__ w2, const float* __restrict__ w3,
    const float* __restrict__ w4, const float* __restrict__ w5,
    const float* __restrict__ w6, const float* __restrict__ w7,
    const float* __restrict__ g_s, const float* __restrict__ g_t,
    short* __restrict__ Wb, float* __restrict__ zs,
    const float* __restrict__ qs_b, const float* __restrict__ vs_b,
    const float* __restrict__ ps_b, const float* __restrict__ qt_b,
    const float* __restrict__ vt_b, const float* __restrict__ pt_b,
    float* __restrict__ bt_s, float* __restrict__ bt_t,
    float* __restrict__ wus, float* __restrict__ wut) {
  const int bid = blockIdx.x, tid = threadIdx.x;
  if (bid < 8192) {                                  // ---- cvt_w ----
    int idx = bid * 256 + tid;
    const float* ws[8] = {w0, w1, w2, w3, w4, w5, w6, w7};
    int wi = idx >> 18, loc = idx & 262143;
    int r = loc >> 9, q = loc & 511;
    float v, g;
    if (wi == 3 || wi == 7) { v = ws[wi][loc]; g = 1.f; }
    else {                                           // transposed, gamma on c_in=r
      v = ws[wi][q * 512 + r];
      g = (wi <= 2) ? g_s[r] : g_t[r];
    }
    Wb[idx] = f2bf(v * g);
  } else if (bid < 8512) {                           // ---- zero 320 KB ----
    zs[(bid - 8192) * 256 + tid] = 0.f;
  } else {                                           // ---- row folds ----
    const int w = tid >> 6, lane = tid & 63;
    const int b = (bid - 8512) * 4 + w;              // [0,2048)
    float s = 0.f;
    if (b < 1024) {                                  // bt = p_w.v_b + p_b
      const bool sp = b < 512;
      const float* W = sp ? w3 : w7;                 // ps_w : pt_w
      const float* vb = sp ? vs_b : vt_b;
      const int r = b & 511;
#pragma unroll
      for (int c = lane; c < 512; c += 64) s += W[r * 512 + c] * vb[c];
#pragma unroll
      for (int off = 32; off > 0; off >>= 1) s += __shfl_xor(s, off);
      if (lane == 0) (sp ? bt_s : bt_t)[r] = s + (sp ? ps_b : pt_b)[r];
    } else {                                         // wu = g * K_w^T.q_b
      const bool sp = b < 1536;
      const float* W = sp ? w1 : w5;                 // ks_w : kt_w
      const float* qb = sp ? qs_b : qt_b;
      const int c = b & 511;
#pragma unroll
      for (int o = lane; o < 512; o += 64) s += W[o * 512 + c] * qb[o];
#pragma unroll
      for (int off = 32; off > 0; off >>= 1) s += __shfl_xor(s, off);
      if (lane == 0)
        (sp ? wus : wut)[c] = s * (sp ? g_s[c] : g_t[c]);
    }
  }
}

// ---------------------------------------------------------------------------
// Transpose + sum-of-squares + u-dot (spatial). src [512][16384] fp32 ->
// dst [16384][512] bf16 (x^T), xb [512][16384] bf16 (straight cast),
// ss[n] += sum_c src[c][n]^2 ; us[n] += sum_c wu[c]*src[c][n].
// ---------------------------------------------------------------------------
__global__ __launch_bounds__(256) void txp_sumsq(
    const float* __restrict__ src, short* __restrict__ dst,
    short* __restrict__ xb, float* __restrict__ ss,
    const float* __restrict__ wu, float* __restrict__ us) {
  constexpr long N = 16384;
  __shared__ short T[64][66];
  __shared__ float part[16][16][4];
  __shared__ float part2[16][16][4];
  const int tid = threadIdx.x;
  const long n0 = (long)blockIdx.x * 64;
  const int c0 = blockIdx.y * 64;
  const int n4 = (tid & 15) * 4;
  float s0 = 0.f, s1 = 0.f, s2 = 0.f, s3 = 0.f;
  float u0 = 0.f, u1 = 0.f, u2 = 0.f, u3 = 0.f;
#pragma unroll
  for (int i = 0; i < 4; ++i) {
    int cl = i * 16 + (tid >> 4);
    float4 v = *(const float4*)&src[(long)(c0 + cl) * N + n0 + n4];
    float wc = wu[c0 + cl];
    s0 += v.x * v.x; s1 += v.y * v.y; s2 += v.z * v.z; s3 += v.w * v.w;
    u0 += wc * v.x; u1 += wc * v.y; u2 += wc * v.z; u3 += wc * v.w;
    short e0 = f2bf(v.x), e1 = f2bf(v.y), e2 = f2bf(v.z), e3 = f2bf(v.w);
    T[n4 + 0][cl] = e0; T[n4 + 1][cl] = e1;
    T[n4 + 2][cl] = e2; T[n4 + 3][cl] = e3;
    uint2 o;
    o.x = (unsigned)(unsigned short)e0 | ((unsigned)(unsigned short)e1 << 16);
    o.y = (unsigned)(unsigned short)e2 | ((unsigned)(unsigned short)e3 << 16);
    *(uint2*)&xb[(long)(c0 + cl) * N + n0 + n4] = o;
  }
  part[tid >> 4][tid & 15][0] = s0; part[tid >> 4][tid & 15][1] = s1;
  part[tid >> 4][tid & 15][2] = s2; part[tid >> 4][tid & 15][3] = s3;
  part2[tid >> 4][tid & 15][0] = u0; part2[tid >> 4][tid & 15][1] = u1;
  part2[tid >> 4][tid & 15][2] = u2; part2[tid >> 4][tid & 15][3] = u3;
  __syncthreads();
  if (tid < 64) {
    float s = 0.f, u = 0.f;
#pragma unroll
    for (int cg = 0; cg < 16; ++cg) {
      s += part[cg][tid >> 2][tid & 3];
      u += part2[cg][tid >> 2][tid & 3];
    }
    atomicAdd(&ss[n0 + tid], s);
    atomicAdd(&us[n0 + tid], u);
  }
#pragma unroll
  for (int p = 0; p < 4; ++p) {
    int nl = p * 16 + (tid >> 4);
    int cl = (tid & 15) * 4;
    uint2 o;
    o.x = (unsigned)(unsigned short)T[nl][cl] |
          ((unsigned)(unsigned short)T[nl][cl + 1] << 16);
    o.y = (unsigned)(unsigned short)T[nl][cl + 2] |
          ((unsigned)(unsigned short)T[nl][cl + 3] << 16);
    *(uint2*)&dst[(n0 + nl) * 512 + c0 + cl] = o;
  }
}

// ---------------------------------------------------------------------------
// Generic NT GEMM: D[i,j] = f( scale * sum_k A[i,k]*B[j,k] ) (+bias,+resid)
// SCALE_MODE: 0 none; 1 row-rms; 2 col-rms; 3 row-recip (softmax denom);
//             4 QK-fold+EXP: val = exp(scale*csc*(rms_row*acc + uvec[col])),
//               rowsum(atomic->rs) of unscaled exp, store val*csc.
// RESID_MODE: 0 none; 1 fp32 same-layout; 2 bf16 same-layout;
//             3 bf16 transposed (residb[j*512+i], uint2-gathered)
// EPI: 0 none; 1 EXP-rowsum (with SCALE4); 3 SUMSQ->rs + dot(wvec)->rs2
// FOLD: z indexes slot tables A{3,7,0,4} B{2,6,1,5} in Wb (weight folds).
//
// T3+T4 counted-vmcnt 2-deep pipeline (this round's change): two tiles of
// loads are kept in flight; per K-step we wait vmcnt(8) — exactly the older
// stage (8 global_load_lds/thread = 4 A + 4 B) — with raw s_barriers and NO
// vmcnt(0) drain in the main loop (m218: counted-vs-drain0 = +38-73%).
//   prologue: stage(t0); stage(t1)
//   iter k:  vmcnt(8); barrier; ds_read+MFMA(k); barrier; stage(k+2)
// asm "memory" clobbers pin all compiler memory ops outside the waits, so
// the only VMEM ops in the loop are the 8 stage loads → the count is exact.
// BM=128/BK=64 dbuf = 64 KB LDS -> 2 blocks/CU (8 waves).
// xor-swizzled LDS (chunk-xor by row & (BK/8-1)): 2-way max, free (m136).
// ---------------------------------------------------------------------------
template <typename OutT, int BIAS_MODE, int SCALE_MODE, int RESID_MODE, int EPI,
          int BM = 128, int FOLD = 0, int BK = 64>
__global__ __launch_bounds__(256, 2) void gemm_nt(
    const short* __restrict__ A, const short* __restrict__ B,
    OutT* __restrict__ D, const float* __restrict__ bias,
    const float* __restrict__ ssv, const float* __restrict__ uvec,
    float* __restrict__ rs, float* __restrict__ rs2,
    const float* __restrict__ wvec,
    const float* __restrict__ residf, const short* __restrict__ residb,
    int K, int lda, int ldb, int ldd,
    long aBatch, long bBatch, long dBatch, long sBatch, float scale) {
  constexpr int WR = BM / 64;                        // wave rows
  constexpr int WC = 4 / WR;                         // wave cols
  constexpr int NW = (128 / WC) / 16;                // B-frags per wave (4 or 8)
  constexpr int CH = BK / 8;                         // 16B chunks per row (8/16)
  constexpr int MSK = CH - 1;
  constexpr int RPR = 256 / CH;                      // rows staged per round
  constexpr int ASZ = BM * BK;                       // elements per buffer
  constexpr int BSZ = 128 * BK;
  __shared__ short As[2 * ASZ];
  __shared__ short Bs[2 * BSZ];
  const int tid = threadIdx.x;
  const int bz = blockIdx.z;
  const long i0 = (long)blockIdx.x * BM;
  const long j0 = (long)blockIdx.y * 128;
  long aOff, bOff;
  if (FOLD) {
    aOff = 262144L * (bz < 2 ? 3 + 4 * bz : 4 * (bz - 2));
    bOff = 262144L * (bz < 2 ? 2 + 4 * bz : 1 + 4 * (bz - 2));
  } else {
    aOff = bz * aBatch; bOff = bz * bBatch;
  }
  const short* Ab = A + aOff + i0 * lda;
  const short* Bb = B + bOff + j0 * ldb;
  const int srow = tid / CH, scol = tid & MSK;
  const int lane = tid & 63;
  const int waveid = tid >> 6;
  const int wr = (waveid / WC) * 64;
  const int wc = (waveid % WC) * 64;
  const int quad = lane >> 4, l15 = lane & 15;

  f32x4 acc[4][NW] = {};

  // stage tile (k0) into buffer buf: exactly 8 global_load_lds per thread
  auto stage = [&](int buf, int k0) {
#pragma unroll
    for (int p = 0; p < BM / RPR; ++p) {
      int row = p * RPR + srow;
      int gc = (scol ^ (row & MSK)) << 3;
      ldscp16(Ab + (long)row * lda + k0 + gc,
              &As[buf * ASZ + p * 2048 + tid * 8]);
    }
#pragma unroll
    for (int p = 0; p < 128 / RPR; ++p) {
      int row = p * RPR + srow;
      int gc = (scol ^ (row & MSK)) << 3;
      ldscp16(Bb + (long)row * ldb + k0 + gc,
              &Bs[buf * BSZ + p * 2048 + tid * 8]);
    }
  };

  stage(0, 0);                                       // tile 0: 8 loads in flight
  if (BK < K) stage(1, BK);                          // tile 1: 16 in flight

  int cur = 0;
  for (int k0 = 0; k0 < K; k0 += BK) {
    // wait for tile k only; tile k+1's loads stay in flight (T4)
    if (k0 + BK < K) {
      asm volatile("s_waitcnt vmcnt(8)" ::: "memory");
    } else {
      asm volatile("s_waitcnt vmcnt(0)" ::: "memory");
    }
    __builtin_amdgcn_s_barrier();                    // publish tile k LDS
    asm volatile("" ::: "memory");
    const short* Ar = &As[cur * ASZ];
    const short* Br = &Bs[cur * BSZ];
#pragma unroll
    for (int kk = 0; kk < BK / 32; ++kk) {
      bf16x8 af[4], bfr[NW];
#pragma unroll
      for (int a = 0; a < 4; ++a) {
        int row = wr + a * 16 + l15;
        int g = kk * 4 + quad;
        af[a] = *(const bf16x8*)&Ar[row * BK + ((g ^ (row & MSK)) << 3)];
      }
#pragma unroll
      for (int b = 0; b < NW; ++b) {
        int row = wc + b * 16 + l15;
        int g = kk * 4 + quad;
        bfr[b] = *(const bf16x8*)&Br[row * BK + ((g ^ (row & MSK)) << 3)];
      }
#pragma unroll
      for (int a = 0; a < 4; ++a)
#pragma unroll
        for (int b = 0; b < NW; ++b)
          acc[a][b] = __builtin_amdgcn_mfma_f32_16x16x32_bf16(af[a], bfr[b], acc[a][b], 0, 0, 0);
    }
    asm volatile("" ::: "memory");
    __builtin_amdgcn_s_barrier();                    // all waves done reading buf
    if (k0 + 2 * BK < K) stage(cur, k0 + 2 * BK);    // re-arm: overwrite buf cur
    cur ^= 1;
  }

  const long Doff = bz * dBatch;
#pragma unroll
  for (int a = 0; a < 4; ++a) {
    const int rb = (int)i0 + wr + a * 16 + quad * 4;   // C/D: row = quad*4+reg
    float rsc[4];
    if (SCALE_MODE == 1 || SCALE_MODE == 4) {
#pragma unroll
      for (int r = 0; r < 4; ++r)
        rsc[r] = 22.627416997969522f /
                 fmaxf(sqrtf(ssv[bz * sBatch + rb + r]), 1e-12f);
    }
    if (SCALE_MODE == 3) {
#pragma unroll
      for (int r = 0; r < 4; ++r)
        rsc[r] = 1.f / ssv[bz * sBatch + rb + r];
    }
    float rp1[4] = {0.f, 0.f, 0.f, 0.f};
    float rp2[4] = {0.f, 0.f, 0.f, 0.f};
#pragma unroll
    for (int b = 0; b < NW; ++b) {
      const int cc = (int)j0 + wc + b * 16 + l15;      // C/D: col = lane&15
      float csc = 1.f, uu = 0.f, wv = 0.f;
      if (SCALE_MODE == 2 || SCALE_MODE == 4)
        csc = 22.627416997969522f /
              fmaxf(sqrtf(ssv[bz * sBatch + cc]), 1e-12f);
      if (SCALE_MODE == 4) uu = uvec[bz * sBatch + cc];
      if (EPI == 3) wv = wvec[cc];
      uint2 rtv;
      if (RESID_MODE == 3)
        rtv = *(const uint2*)&residb[(long)cc * 512 + rb];
#pragma unroll
      for (int r = 0; r < 4; ++r) {
        float val;
        if (SCALE_MODE == 4) {
          val = __expf(scale * csc * (rsc[r] * acc[a][b][r] + uu));
          rp1[r] += val;
          val *= csc;
        } else {
          val = acc[a][b][r] * scale;
          if (SCALE_MODE == 1 || SCALE_MODE == 3) val *= rsc[r];
          if (SCALE_MODE == 2) val *= csc;
        }
        if (BIAS_MODE == 1) val += bias[rb + r];
        if (BIAS_MODE == 2) val += bias[cc];
        const long off = Doff + (long)(rb + r) * ldd + cc;
        if (RESID_MODE == 1) val += residf[off];
        if (RESID_MODE == 2) val += bf2f(residb[off]);
        if (RESID_MODE == 3) val += bf2f(((const short*)&rtv)[r]);
        stv(D + off, val);
        if (EPI == 3) { rp1[r] += val * val; rp2[r] += val * wv; }
      }
    }
    if (EPI == 1 || EPI == 3) {
#pragma unroll
      for (int r = 0; r < 4; ++r) {
        float s = rp1[r];
#pragma unroll
        for (int off = 1; off < 16; off <<= 1) s += __shfl_xor(s, off);
        if (l15 == 0) atomicAdd(&rs[bz * sBatch + rb + r], s);
      }
      if (EPI == 3) {
#pragma unroll
        for (int r = 0; r < 4; ++r) {
          float s = rp2[r];
#pragma unroll
          for (int off = 1; off < 16; off <<= 1) s += __shfl_xor(s, off);
          if (l15 == 0) atomicAdd(&rs2[bz * sBatch + rb + r], s);
        }
      }
    }
  }
}

// ---------------------------------------------------------------------------
// Temporal attention v5 — QK-folded. h2: [16384][512] bf16, Tt = Mt.h2
// [16384][512] bf16. S[i,j] = scale*(rms_i*rms_j*(h2_i.Tt_j) + rms_j*ut_j).
// Block per pixel; V = rms-folded h2 (V projection folded into out-GEMM).
// ---------------------------------------------------------------------------
__global__ __launch_bounds__(256) void temporal_attn_v5(
    const short* __restrict__ h2, const short* __restrict__ Tt,
    const float* __restrict__ ss, const float* __restrict__ ut,
    const int* __restrict__ wndp, short* __restrict__ o, float scale) {
  constexpr int RS = 520;                            // 512 + 8 pad
  __shared__ short hq[16 * RS];
  __shared__ short tk[16 * RS];
  __shared__ float Plds[16][17];
  const int tid = threadIdx.x;
  const int w = tid >> 6, lane = tid & 63;
  const int hw = blockIdx.x;
  const int wnd = *wndp;

#pragma unroll
  for (int i = 0; i < 8; ++i) {
    int ci = w * 8 + i;                              // 32 rows: 0..15 h2, 16..31 Tt
    int t = ci & 15;
    const short* src = (ci < 16) ? h2 : Tt;
    short* dst = (ci < 16) ? hq : tk;
    ldscp16(src + (long)(t * 1024 + hw) * 512 + lane * 8,
            dst + t * RS + lane * 8);
  }
  const int c0 = lane * 8;
  uint4 vch[16];
#pragma unroll
  for (int tp = 0; tp < 16; ++tp)
    vch[tp] = *(const uint4*)(h2 + (long)(tp * 1024 + hw) * 512 + c0);
  __syncthreads();

  if (w == 0) {
    const int quad = lane >> 4, m = lane & 15;
    f32x4 sacc = {};
#pragma unroll
    for (int s = 0; s < 16; ++s) {
      bf16x8 aq = *(const bf16x8*)&hq[m * RS + quad * 8 + s * 32];
      bf16x8 bk = *(const bf16x8*)&tk[m * RS + quad * 8 + s * 32];
      sacc = __builtin_amdgcn_mfma_f32_16x16x32_bf16(aq, bk, sacc, 0, 0, 0);
    }
    const float rmsj = 22.627416997969522f /
                       fmaxf(sqrtf(ss[m * 1024 + hw]), 1e-12f);
    const float uj = ut[m * 1024 + hw];
#pragma unroll
    for (int r = 0; r < 4; ++r) {
      const int i = quad * 4 + r;
      const int j = m;
      const float rmsi = 22.627416997969522f /
                         fmaxf(sqrtf(ss[i * 1024 + hw]), 1e-12f);
      const bool allowed = (j <= i) && (wnd <= 0 || (i - j) < wnd);
      float val = allowed ? scale * (rmsi * rmsj * sacc[r] + rmsj * uj) : -1e30f;
      float mx = val;
#pragma unroll
      for (int off = 1; off < 16; off <<= 1) mx = fmaxf(mx, __shfl_xor(mx, off));
      float e = allowed ? __expf(val - mx) : 0.f;
      float sum = e;
#pragma unroll
      for (int off = 1; off < 16; off <<= 1) sum += __shfl_xor(sum, off);
      Plds[i][j] = (e / sum) * rmsj;                 // rms_j folded into P (V-fold)
    }
  }
  __syncthreads();

#pragma unroll
  for (int r = 0; r < 4; ++r) {
    const int t = w * 4 + r;
    const int tlo = (wnd > 0 && t - wnd + 1 > 0) ? t - wnd + 1 : 0;
    float a0 = 0.f, a1 = 0.f, a2 = 0.f, a3 = 0.f,
          a4 = 0.f, a5 = 0.f, a6 = 0.f, a7 = 0.f;
#pragma unroll
    for (int tp = 0; tp < 16; ++tp) {
      const float p = (tp >= tlo && tp <= t) ? Plds[t][tp] : 0.f;
      const uint4 vv = vch[tp];
      a0 += p * blo(vv.x); a1 += p * bhi(vv.x);
      a2 += p * blo(vv.y); a3 += p * bhi(vv.y);
      a4 += p * blo(vv.z); a5 += p * bhi(vv.z);
      a6 += p * blo(vv.w); a7 += p * bhi(vv.w);
    }
    uint4 ov;
    ov.x = packbf(a0, a1); ov.y = packbf(a2, a3);
    ov.z = packbf(a4, a5); ov.w = packbf(a6, a7);
    *(uint4*)(o + (long)(t * 1024 + hw) * 512 + c0) = ov;
  }
}

// ---------------------------------------------------------------------------
// Launch
// ---------------------------------------------------------------------------
extern "C" void kernel_launch(void* const* d_in, const int* in_sizes, int n_in,
                              void* d_out, int out_size, void* d_ws, size_t ws_size,
                              hipStream_t stream) {
  const float* x    = (const float*)d_in[0];
  const float* qs_w = (const float*)d_in[1];
  const float* qs_b = (const float*)d_in[2];
  const float* ks_w = (const float*)d_in[3];
  const float* ks_b = (const float*)d_in[4];
  const float* vs_w = (const float*)d_in[5];
  const float* vs_b = (const float*)d_in[6];
  const float* ps_w = (const float*)d_in[7];
  const float* ps_b = (const float*)d_in[8];
  const float* qt_w = (const float*)d_in[9];
  const float* qt_b = (const float*)d_in[10];
  const float* kt_w = (const float*)d_in[11];
  const float* kt_b = (const float*)d_in[12];
  const float* vt_w = (const float*)d_in[13];
  const float* vt_b = (const float*)d_in[14];
  const float* pt_w = (const float*)d_in[15];
  const float* pt_b = (const float*)d_in[16];
  const float* g_s  = (const float*)d_in[17];
  const float* g_t  = (const float*)d_in[18];
  const int*   wnd  = (const int*)d_in[19];
  float* out = (float*)d_out;
  (void)ks_b; (void)kt_b;   // K biases appear only via wu (zero cross-terms cancel)

  // workspace carve (~136 MB)
  char* w = (char*)d_ws;
  short* Wb   = (short*)(w);                               // 4 MB: 8 weight slots
  float* ss_s = (float*)(w + (4L << 20));                  // 64 KB (zeroed group start)
  float* ss_t = (float*)(w + (4L << 20) + (64 << 10));     // 64 KB
  float* rsum = (float*)(w + (4L << 20) + (128 << 10));    // 64 KB
  float* us   = (float*)(w + (4L << 20) + (192 << 10));    // 64 KB
  float* ut   = (float*)(w + (4L << 20) + (256 << 10));    // 64 KB (zeroed group end)
  float* bt_s = (float*)(w + (4L << 20) + (320 << 10));    // 2 KB folded bias
  float* bt_t = (float*)(w + (4L << 20) + (324 << 10));    // 2 KB
  float* wus  = (float*)(w + (4L << 20) + (328 << 10));    // 2 KB u-weights
  float* wut  = (float*)(w + (4L << 20) + (332 << 10));    // 2 KB
  short* WF   = (short*)(w + (4L << 20) + (512 << 10));    // 2 MB: Wpv_s|Wpv_t|Mqk_s|Mqk_t
  short* Wpv  = WF;
  short* Mqk  = WF + 2 * 262144;
  short* hb   = (short*)(w + (8L << 20));                  // 16 MB: [16384][512] bf16 x^T
  short* Tb   = (short*)(w + (24L << 20));                 // 16 MB: [16384][512] T = M.h
  short* xb   = (short*)(w + (40L << 20));                 // 16 MB: [512][16384] bf16 x
  short* oT   = (short*)(w + (56L << 20));                 // 16 MB: [16384][512] h~
  short* h2   = (short*)(w + (72L << 20));                 // 16 MB: [16384][512]
  short* S    = (short*)(w + (88L << 20));                 // 32 MB: [16][1024][1024]
  (void)in_sizes; (void)n_in; (void)out_size; (void)ws_size;

  const float scale = 0.04419417382415922f;                // 512^-0.5

  setup_all<<<9024, 256, 0, stream>>>(
      qs_w, ks_w, vs_w, ps_w, qt_w, kt_w, vt_w, pt_w, g_s, g_t, Wb, ss_s,
      qs_b, vs_b, ps_b, qt_b, vt_b, pt_b, bt_s, bt_t, wus, wut);
  // Merged weight folds (z slot tables): z0 Wpv_s=ps.vs_g, z1 Wpv_t=pt.vt_g,
  // z2 Mqk_s=qs_g^T.ks_g, z3 Mqk_t=qt_g^T.kt_g
  gemm_nt<short, 0, 0, 0, 0, 128, 1><<<dim3(4, 4, 4), 256, 0, stream>>>(
      Wb, Wb, WF, nullptr, nullptr, nullptr, nullptr, nullptr, nullptr,
      nullptr, nullptr, 512, 512, 512, 512, 0, 0, 262144L, 0, 1.f);

  // ---------------- spatial ----------------
  txp_sumsq<<<dim3(256, 8, 1), 256, 0, stream>>>(x, hb, xb, ss_s, wus, us);
  // T[n][a] = hb[n,:] . Mqk_s[a,:]
  gemm_nt<short, 0, 0, 0, 0, 128><<<dim3(128, 4, 1), 256, 0, stream>>>(
      hb, Mqk, Tb, nullptr, nullptr, nullptr, nullptr, nullptr, nullptr,
      nullptr, nullptr, 512, 512, 512, 512, 0, 0, 0, 0, 1.f);
  // expS'[t][l][m] = exp(scale*rms_m*(rms_l*(hb_l.T_m)+us_m))*rms_m ; rsum+=
  gemm_nt<short, 0, 4, 0, 1, 128><<<dim3(8, 8, 16), 256, 0, stream>>>(
      hb, Tb, S, nullptr, ss_s, us, rsum, nullptr, nullptr, nullptr, nullptr,
      512, 512, 512, 1024,
      1024L * 512, 1024L * 512, 1024L * 1024, 1024, scale);
  // h~[n][c] = (1/rsum) * sum_m expS'[l,m] * xb[c,m]
  gemm_nt<short, 0, 3, 0, 0, 128><<<dim3(8, 4, 16), 256, 0, stream>>>(
      S, xb, oT, nullptr, rsum, nullptr, nullptr, nullptr, nullptr,
      nullptr, nullptr, 1024, 1024, 16384, 512,
      1024L * 1024, 1024L, 1024L * 512, 1024, 1.f);
  // h2[n][c] = bf16( hb[n][c] + bt_s[c] + (oT.Wpv_s^T)[n][c] );
  //   ss_t += val^2 ; ut += val*wut[c]
  gemm_nt<short, 2, 0, 2, 3, 128><<<dim3(128, 4, 1), 256, 0, stream>>>(
      oT, Wpv, h2, bt_s, nullptr, nullptr, ss_t, ut, wut, nullptr, hb,
      512, 512, 512, 512, 0, 0, 0, 1024, 1.f);

  // ---------------- temporal ----------------
  // Tt[n][a] = h2[n,:] . Mqk_t[a,:]
  gemm_nt<short, 0, 0, 0, 0, 128><<<dim3(128, 4, 1), 256, 0, stream>>>(
      h2, Mqk + 262144, Tb, nullptr, nullptr, nullptr, nullptr, nullptr,
      nullptr, nullptr, nullptr, 512, 512, 512, 512, 0, 0, 0, 0, 1.f);
  temporal_attn_v5<<<1024, 256, 0, stream>>>(h2, Tb, ss_t, ut, wnd, oT, scale);
  // out[c,n] = h2[n][c] + bt_t[c] + Wpv_t[c,:] . h~[n,:]   (fp32, c-major)
  gemm_nt<float, 1, 0, 3, 0, 128><<<dim3(4, 128, 1), 256, 0, stream>>>(
      Wpv + 262144, oT, out, bt_t, nullptr, nullptr, nullptr, nullptr,
      nullptr, nullptr, h2, 512, 512, 512, 16384, 0, 0, 0, 0, 1.f);
}

// Round 4
// 301.304 us; speedup vs baseline: 1.0206x; 1.0138x over previous
//
#include <hip/hip_runtime.h>

// ---------------------------------------------------------------------------
// Types & helpers
// ---------------------------------------------------------------------------
typedef __attribute__((ext_vector_type(8))) short bf16x8;
typedef __attribute__((ext_vector_type(4))) float f32x4;

__device__ __forceinline__ short f2bf(float f) {
  union { float f; unsigned u; } a; a.f = f;
  unsigned r = a.u + 0x7fffu + ((a.u >> 16) & 1u);   // RNE
  return (short)(r >> 16);
}
__device__ __forceinline__ float bf2f(short s) {
  union { unsigned u; float f; } a;
  a.u = ((unsigned)(unsigned short)s) << 16; return a.f;
}
__device__ __forceinline__ float blo(unsigned u) { union { unsigned u; float f; } a; a.u = u << 16; return a.f; }
__device__ __forceinline__ float bhi(unsigned u) { union { unsigned u; float f; } a; a.u = u & 0xffff0000u; return a.f; }
__device__ __forceinline__ unsigned packbf(float lo, float hi) {
  return (unsigned)(unsigned short)f2bf(lo) | ((unsigned)(unsigned short)f2bf(hi) << 16);
}
__device__ __forceinline__ void ldscp16(const void* g, void* l) {
  __builtin_amdgcn_global_load_lds((const __attribute__((address_space(1))) void*)g,
                                   (__attribute__((address_space(3))) void*)l, 16, 0, 0);
}
__device__ __forceinline__ void stv(float* p, float v) { *p = v; }
__device__ __forceinline__ void stv(short* p, float v) { *p = f2bf(v); }

// ---------------------------------------------------------------------------
// Merged setup. Blocks:
//  [0,8192)      cvt_w: slots 0 qs^T_g,1 ks^T_g,2 vs^T_g,3 ps,4 qt^T_g,
//                5 kt^T_g,6 vt^T_g,7 pt  (q/k/v transposed [c_in][c_out],
//                gamma folded on c_in; needed by the fold GEMMs)
//  [8192,8512)   zero 320 KB (ss_s|ss_t|rsum|us|ut)
//  [8512,9024)   row-folds, 4 waves/block, row b = (bid-8512)*4+wave:
//     b<512   : bt_s[b]   = ps_w[b,:].vs_b + ps_b[b]
//     b<1024  : bt_t[...] = pt_w.vt_b + pt_b
//     b<1536  : wus[c]    = g_s[c] * sum_o ks_w[o][c]*qs_b[o]   (u-vector wt)
//     b<2048  : wut[c]    = g_t[c] * sum_o kt_w[o][c]*qt_b[o]
// ---------------------------------------------------------------------------
__global__ __launch_bounds__(256) void setup_all(
    const float* __restrict__ w0, const float* __restrict__ w1,
    const float* __restrict__ w2, const float* __restrict__ w3,
    const float* __restrict__ w4, const float* __restrict__ w5,
    const float* __restrict__ w6, const float* __restrict__ w7,
    const float* __restrict__ g_s, const float* __restrict__ g_t,
    short* __restrict__ Wb, float* __restrict__ zs,
    const float* __restrict__ qs_b, const float* __restrict__ vs_b,
    const float* __restrict__ ps_b, const float* __restrict__ qt_b,
    const float* __restrict__ vt_b, const float* __restrict__ pt_b,
    float* __restrict__ bt_s, float* __restrict__ bt_t,
    float* __restrict__ wus, float* __restrict__ wut) {
  const int bid = blockIdx.x, tid = threadIdx.x;
  if (bid < 8192) {                                  // ---- cvt_w ----
    int idx = bid * 256 + tid;
    const float* ws[8] = {w0, w1, w2, w3, w4, w5, w6, w7};
    int wi = idx >> 18, loc = idx & 262143;
    int r = loc >> 9, q = loc & 511;
    float v, g;
    if (wi == 3 || wi == 7) { v = ws[wi][loc]; g = 1.f; }
    else {                                           // transposed, gamma on c_in=r
      v = ws[wi][q * 512 + r];
      g = (wi <= 2) ? g_s[r] : g_t[r];
    }
    Wb[idx] = f2bf(v * g);
  } else if (bid < 8512) {                           // ---- zero 320 KB ----
    zs[(bid - 8192) * 256 + tid] = 0.f;
  } else {                                           // ---- row folds ----
    const int w = tid >> 6, lane = tid & 63;
    const int b = (bid - 8512) * 4 + w;              // [0,2048)
    float s = 0.f;
    if (b < 1024) {                                  // bt = p_w.v_b + p_b
      const bool sp = b < 512;
      const float* W = sp ? w3 : w7;                 // ps_w : pt_w
      const float* vb = sp ? vs_b : vt_b;
      const int r = b & 511;
#pragma unroll
      for (int c = lane; c < 512; c += 64) s += W[r * 512 + c] * vb[c];
#pragma unroll
      for (int off = 32; off > 0; off >>= 1) s += __shfl_xor(s, off);
      if (lane == 0) (sp ? bt_s : bt_t)[r] = s + (sp ? ps_b : pt_b)[r];
    } else {                                         // wu = g * K_w^T.q_b
      const bool sp = b < 1536;
      const float* W = sp ? w1 : w5;                 // ks_w : kt_w
      const float* qb = sp ? qs_b : qt_b;
      const int c = b & 511;
#pragma unroll
      for (int o = lane; o < 512; o += 64) s += W[o * 512 + c] * qb[o];
#pragma unroll
      for (int off = 32; off > 0; off >>= 1) s += __shfl_xor(s, off);
      if (lane == 0)
        (sp ? wus : wut)[c] = s * (sp ? g_s[c] : g_t[c]);
    }
  }
}

// ---------------------------------------------------------------------------
// Transpose + sum-of-squares + u-dot (spatial). src [512][16384] fp32 ->
// dst [16384][512] bf16 (x^T), xb [512][16384] bf16 (straight cast),
// ss[n] += sum_c src[c][n]^2 ; us[n] += sum_c wu[c]*src[c][n].
// ---------------------------------------------------------------------------
__global__ __launch_bounds__(256) void txp_sumsq(
    const float* __restrict__ src, short* __restrict__ dst,
    short* __restrict__ xb, float* __restrict__ ss,
    const float* __restrict__ wu, float* __restrict__ us) {
  constexpr long N = 16384;
  __shared__ short T[64][66];
  __shared__ float part[16][16][4];
  __shared__ float part2[16][16][4];
  const int tid = threadIdx.x;
  const long n0 = (long)blockIdx.x * 64;
  const int c0 = blockIdx.y * 64;
  const int n4 = (tid & 15) * 4;
  float s0 = 0.f, s1 = 0.f, s2 = 0.f, s3 = 0.f;
  float u0 = 0.f, u1 = 0.f, u2 = 0.f, u3 = 0.f;
#pragma unroll
  for (int i = 0; i < 4; ++i) {
    int cl = i * 16 + (tid >> 4);
    float4 v = *(const float4*)&src[(long)(c0 + cl) * N + n0 + n4];
    float wc = wu[c0 + cl];
    s0 += v.x * v.x; s1 += v.y * v.y; s2 += v.z * v.z; s3 += v.w * v.w;
    u0 += wc * v.x; u1 += wc * v.y; u2 += wc * v.z; u3 += wc * v.w;
    short e0 = f2bf(v.x), e1 = f2bf(v.y), e2 = f2bf(v.z), e3 = f2bf(v.w);
    T[n4 + 0][cl] = e0; T[n4 + 1][cl] = e1;
    T[n4 + 2][cl] = e2; T[n4 + 3][cl] = e3;
    uint2 o;
    o.x = (unsigned)(unsigned short)e0 | ((unsigned)(unsigned short)e1 << 16);
    o.y = (unsigned)(unsigned short)e2 | ((unsigned)(unsigned short)e3 << 16);
    *(uint2*)&xb[(long)(c0 + cl) * N + n0 + n4] = o;
  }
  part[tid >> 4][tid & 15][0] = s0; part[tid >> 4][tid & 15][1] = s1;
  part[tid >> 4][tid & 15][2] = s2; part[tid >> 4][tid & 15][3] = s3;
  part2[tid >> 4][tid & 15][0] = u0; part2[tid >> 4][tid & 15][1] = u1;
  part2[tid >> 4][tid & 15][2] = u2; part2[tid >> 4][tid & 15][3] = u3;
  __syncthreads();
  if (tid < 64) {
    float s = 0.f, u = 0.f;
#pragma unroll
    for (int cg = 0; cg < 16; ++cg) {
      s += part[cg][tid >> 2][tid & 3];
      u += part2[cg][tid >> 2][tid & 3];
    }
    atomicAdd(&ss[n0 + tid], s);
    atomicAdd(&us[n0 + tid], u);
  }
#pragma unroll
  for (int p = 0; p < 4; ++p) {
    int nl = p * 16 + (tid >> 4);
    int cl = (tid & 15) * 4;
    uint2 o;
    o.x = (unsigned)(unsigned short)T[nl][cl] |
          ((unsigned)(unsigned short)T[nl][cl + 1] << 16);
    o.y = (unsigned)(unsigned short)T[nl][cl + 2] |
          ((unsigned)(unsigned short)T[nl][cl + 3] << 16);
    *(uint2*)&dst[(n0 + nl) * 512 + c0 + cl] = o;
  }
}

// ---------------------------------------------------------------------------
// Generic NT GEMM: D[i,j] = f( scale * sum_k A[i,k]*B[j,k] ) (+bias,+resid)
// SCALE_MODE: 0 none; 1 row-rms; 2 col-rms; 3 row-recip (softmax denom);
//             4 QK-fold+EXP: val = exp(scale*csc*(rms_row*acc + uvec[col])),
//               rowsum(atomic->rs) of unscaled exp, store val*csc.
// RESID_MODE: 0 none; 1 fp32 same-layout; 2 bf16 same-layout;
//             3 bf16 transposed (residb[j*512+i], uint2-gathered)
// EPI: 0 none; 1 EXP-rowsum (with SCALE4); 3 SUMSQ->rs + dot(wvec)->rs2
// FOLD: z indexes slot tables A{3,7,0,4} B{2,6,1,5} in Wb (weight folds).
// SWZ: bijective XCD chunk swizzle (m204) on the flattened block index —
//      each XCD's contiguous chunk shares operand panels in its private L2
//      (x-fastest dispatch otherwise round-robins panel-sharing blocks
//      across 8 non-coherent L2s; FETCH showed 74 MB vs 32 MB unique).
//
// Round-3 structure: m97-style single-buffer 2-barrier loop at BK=64 ->
// 32 KB LDS -> __launch_bounds__(256,4) -> 4 blocks/CU (16 waves, 4/SIMD).
// Rationale: dbuf+counted-vmcnt measured NULL (T4 requires 8-phase regime);
// m97/m114 evidence says this structure's latency hiding is cross-block
// TLP, which 64 KB dbuf halved. VGPR 88 <= 128 so 4 blocks fit.
// xor-swizzled LDS (chunk-xor by row & (BK/8-1)): 2-way max, free (m136).
// ---------------------------------------------------------------------------
template <typename OutT, int BIAS_MODE, int SCALE_MODE, int RESID_MODE, int EPI,
          int BM = 128, int FOLD = 0, int BK = 64, int SWZ = 0>
__global__ __launch_bounds__(256, 4) void gemm_nt(
    const short* __restrict__ A, const short* __restrict__ B,
    OutT* __restrict__ D, const float* __restrict__ bias,
    const float* __restrict__ ssv, const float* __restrict__ uvec,
    float* __restrict__ rs, float* __restrict__ rs2,
    const float* __restrict__ wvec,
    const float* __restrict__ residf, const short* __restrict__ residb,
    int K, int lda, int ldb, int ldd,
    long aBatch, long bBatch, long dBatch, long sBatch, float scale) {
  constexpr int WR = BM / 64;                        // wave rows
  constexpr int WC = 4 / WR;                         // wave cols
  constexpr int NW = (128 / WC) / 16;                // B-frags per wave (4 or 8)
  constexpr int CH = BK / 8;                         // 16B chunks per row
  constexpr int MSK = CH - 1;
  constexpr int RPR = 256 / CH;                      // rows staged per round
  __shared__ short As[BM * BK];
  __shared__ short Bs[128 * BK];
  const int tid = threadIdx.x;

  // ---- block-index decode (optionally XCD-chunk-swizzled, bijective) ----
  int lin = blockIdx.x + gridDim.x * (blockIdx.y + gridDim.y * blockIdx.z);
  if (SWZ) {
    const int nwg = gridDim.x * gridDim.y * gridDim.z;
    const int q = nwg >> 3, r = nwg & 7;
    const int xcd = lin & 7, idx = lin >> 3;
    lin = (xcd < r ? xcd * (q + 1) : r * (q + 1) + (xcd - r) * q) + idx;
  }
  const int bx = lin % gridDim.x;
  const int t1 = lin / gridDim.x;
  const int by = t1 % gridDim.y;
  const int bz = t1 / gridDim.y;

  const long i0 = (long)bx * BM;
  const long j0 = (long)by * 128;
  long aOff, bOff;
  if (FOLD) {
    aOff = 262144L * (bz < 2 ? 3 + 4 * bz : 4 * (bz - 2));
    bOff = 262144L * (bz < 2 ? 2 + 4 * bz : 1 + 4 * (bz - 2));
  } else {
    aOff = bz * aBatch; bOff = bz * bBatch;
  }
  const short* Ab = A + aOff + i0 * lda;
  const short* Bb = B + bOff + j0 * ldb;
  const int srow = tid / CH, scol = tid & MSK;
  const int lane = tid & 63;
  const int waveid = tid >> 6;
  const int wr = (waveid / WC) * 64;
  const int wc = (waveid % WC) * 64;
  const int quad = lane >> 4, l15 = lane & 15;

  f32x4 acc[4][NW] = {};

  for (int k0 = 0; k0 < K; k0 += BK) {
    __syncthreads();
#pragma unroll
    for (int p = 0; p < BM / RPR; ++p) {
      int row = p * RPR + srow;
      int gc = (scol ^ (row & MSK)) << 3;
      ldscp16(Ab + (long)row * lda + k0 + gc, &As[p * 2048 + tid * 8]);
    }
#pragma unroll
    for (int p = 0; p < 128 / RPR; ++p) {
      int row = p * RPR + srow;
      int gc = (scol ^ (row & MSK)) << 3;
      ldscp16(Bb + (long)row * ldb + k0 + gc, &Bs[p * 2048 + tid * 8]);
    }
    __syncthreads();
#pragma unroll
    for (int kk = 0; kk < BK / 32; ++kk) {
      bf16x8 af[4], bfr[NW];
#pragma unroll
      for (int a = 0; a < 4; ++a) {
        int row = wr + a * 16 + l15;
        int g = kk * 4 + quad;
        af[a] = *(const bf16x8*)&As[row * BK + ((g ^ (row & MSK)) << 3)];
      }
#pragma unroll
      for (int b = 0; b < NW; ++b) {
        int row = wc + b * 16 + l15;
        int g = kk * 4 + quad;
        bfr[b] = *(const bf16x8*)&Bs[row * BK + ((g ^ (row & MSK)) << 3)];
      }
#pragma unroll
      for (int a = 0; a < 4; ++a)
#pragma unroll
        for (int b = 0; b < NW; ++b)
          acc[a][b] = __builtin_amdgcn_mfma_f32_16x16x32_bf16(af[a], bfr[b], acc[a][b], 0, 0, 0);
    }
  }

  const long Doff = bz * dBatch;
#pragma unroll
  for (int a = 0; a < 4; ++a) {
    const int rb = (int)i0 + wr + a * 16 + quad * 4;   // C/D: row = quad*4+reg
    float rsc[4];
    if (SCALE_MODE == 1 || SCALE_MODE == 4) {
#pragma unroll
      for (int r = 0; r < 4; ++r)
        rsc[r] = 22.627416997969522f /
                 fmaxf(sqrtf(ssv[bz * sBatch + rb + r]), 1e-12f);
    }
    if (SCALE_MODE == 3) {
#pragma unroll
      for (int r = 0; r < 4; ++r)
        rsc[r] = 1.f / ssv[bz * sBatch + rb + r];
    }
    float rp1[4] = {0.f, 0.f, 0.f, 0.f};
    float rp2[4] = {0.f, 0.f, 0.f, 0.f};
#pragma unroll
    for (int b = 0; b < NW; ++b) {
      const int cc = (int)j0 + wc + b * 16 + l15;      // C/D: col = lane&15
      float csc = 1.f, uu = 0.f, wv = 0.f;
      if (SCALE_MODE == 2 || SCALE_MODE == 4)
        csc = 22.627416997969522f /
              fmaxf(sqrtf(ssv[bz * sBatch + cc]), 1e-12f);
      if (SCALE_MODE == 4) uu = uvec[bz * sBatch + cc];
      if (EPI == 3) wv = wvec[cc];
      uint2 rtv;
      if (RESID_MODE == 3)
        rtv = *(const uint2*)&residb[(long)cc * 512 + rb];
#pragma unroll
      for (int r = 0; r < 4; ++r) {
        float val;
        if (SCALE_MODE == 4) {
          val = __expf(scale * csc * (rsc[r] * acc[a][b][r] + uu));
          rp1[r] += val;
          val *= csc;
        } else {
          val = acc[a][b][r] * scale;
          if (SCALE_MODE == 1 || SCALE_MODE == 3) val *= rsc[r];
          if (SCALE_MODE == 2) val *= csc;
        }
        if (BIAS_MODE == 1) val += bias[rb + r];
        if (BIAS_MODE == 2) val += bias[cc];
        const long off = Doff + (long)(rb + r) * ldd + cc;
        if (RESID_MODE == 1) val += residf[off];
        if (RESID_MODE == 2) val += bf2f(residb[off]);
        if (RESID_MODE == 3) val += bf2f(((const short*)&rtv)[r]);
        stv(D + off, val);
        if (EPI == 3) { rp1[r] += val * val; rp2[r] += val * wv; }
      }
    }
    if (EPI == 1 || EPI == 3) {
#pragma unroll
      for (int r = 0; r < 4; ++r) {
        float s = rp1[r];
#pragma unroll
        for (int off = 1; off < 16; off <<= 1) s += __shfl_xor(s, off);
        if (l15 == 0) atomicAdd(&rs[bz * sBatch + rb + r], s);
      }
      if (EPI == 3) {
#pragma unroll
        for (int r = 0; r < 4; ++r) {
          float s = rp2[r];
#pragma unroll
          for (int off = 1; off < 16; off <<= 1) s += __shfl_xor(s, off);
          if (l15 == 0) atomicAdd(&rs2[bz * sBatch + rb + r], s);
        }
      }
    }
  }
}

// ---------------------------------------------------------------------------
// Temporal attention v5 — QK-folded. h2: [16384][512] bf16, Tt = Mt.h2
// [16384][512] bf16. S[i,j] = scale*(rms_i*rms_j*(h2_i.Tt_j) + rms_j*ut_j).
// Block per pixel; V = rms-folded h2 (V projection folded into out-GEMM).
// ---------------------------------------------------------------------------
__global__ __launch_bounds__(256) void temporal_attn_v5(
    const short* __restrict__ h2, const short* __restrict__ Tt,
    const float* __restrict__ ss, const float* __restrict__ ut,
    const int* __restrict__ wndp, short* __restrict__ o, float scale) {
  constexpr int RS = 520;                            // 512 + 8 pad
  __shared__ short hq[16 * RS];
  __shared__ short tk[16 * RS];
  __shared__ float Plds[16][17];
  const int tid = threadIdx.x;
  const int w = tid >> 6, lane = tid & 63;
  const int hw = blockIdx.x;
  const int wnd = *wndp;

#pragma unroll
  for (int i = 0; i < 8; ++i) {
    int ci = w * 8 + i;                              // 32 rows: 0..15 h2, 16..31 Tt
    int t = ci & 15;
    const short* src = (ci < 16) ? h2 : Tt;
    short* dst = (ci < 16) ? hq : tk;
    ldscp16(src + (long)(t * 1024 + hw) * 512 + lane * 8,
            dst + t * RS + lane * 8);
  }
  const int c0 = lane * 8;
  uint4 vch[16];
#pragma unroll
  for (int tp = 0; tp < 16; ++tp)
    vch[tp] = *(const uint4*)(h2 + (long)(tp * 1024 + hw) * 512 + c0);
  __syncthreads();

  if (w == 0) {
    const int quad = lane >> 4, m = lane & 15;
    f32x4 sacc = {};
#pragma unroll
    for (int s = 0; s < 16; ++s) {
      bf16x8 aq = *(const bf16x8*)&hq[m * RS + quad * 8 + s * 32];
      bf16x8 bk = *(const bf16x8*)&tk[m * RS + quad * 8 + s * 32];
      sacc = __builtin_amdgcn_mfma_f32_16x16x32_bf16(aq, bk, sacc, 0, 0, 0);
    }
    const float rmsj = 22.627416997969522f /
                       fmaxf(sqrtf(ss[m * 1024 + hw]), 1e-12f);
    const float uj = ut[m * 1024 + hw];
#pragma unroll
    for (int r = 0; r < 4; ++r) {
      const int i = quad * 4 + r;
      const int j = m;
      const float rmsi = 22.627416997969522f /
                         fmaxf(sqrtf(ss[i * 1024 + hw]), 1e-12f);
      const bool allowed = (j <= i) && (wnd <= 0 || (i - j) < wnd);
      float val = allowed ? scale * (rmsi * rmsj * sacc[r] + rmsj * uj) : -1e30f;
      float mx = val;
#pragma unroll
      for (int off = 1; off < 16; off <<= 1) mx = fmaxf(mx, __shfl_xor(mx, off));
      float e = allowed ? __expf(val - mx) : 0.f;
      float sum = e;
#pragma unroll
      for (int off = 1; off < 16; off <<= 1) sum += __shfl_xor(sum, off);
      Plds[i][j] = (e / sum) * rmsj;                 // rms_j folded into P (V-fold)
    }
  }
  __syncthreads();

#pragma unroll
  for (int r = 0; r < 4; ++r) {
    const int t = w * 4 + r;
    const int tlo = (wnd > 0 && t - wnd + 1 > 0) ? t - wnd + 1 : 0;
    float a0 = 0.f, a1 = 0.f, a2 = 0.f, a3 = 0.f,
          a4 = 0.f, a5 = 0.f, a6 = 0.f, a7 = 0.f;
#pragma unroll
    for (int tp = 0; tp < 16; ++tp) {
      const float p = (tp >= tlo && tp <= t) ? Plds[t][tp] : 0.f;
      const uint4 vv = vch[tp];
      a0 += p * blo(vv.x); a1 += p * bhi(vv.x);
      a2 += p * blo(vv.y); a3 += p * bhi(vv.y);
      a4 += p * blo(vv.z); a5 += p * bhi(vv.z);
      a6 += p * blo(vv.w); a7 += p * bhi(vv.w);
    }
    uint4 ov;
    ov.x = packbf(a0, a1); ov.y = packbf(a2, a3);
    ov.z = packbf(a4, a5); ov.w = packbf(a6, a7);
    *(uint4*)(o + (long)(t * 1024 + hw) * 512 + c0) = ov;
  }
}

// ---------------------------------------------------------------------------
// Launch
// ---------------------------------------------------------------------------
extern "C" void kernel_launch(void* const* d_in, const int* in_sizes, int n_in,
                              void* d_out, int out_size, void* d_ws, size_t ws_size,
                              hipStream_t stream) {
  const float* x    = (const float*)d_in[0];
  const float* qs_w = (const float*)d_in[1];
  const float* qs_b = (const float*)d_in[2];
  const float* ks_w = (const float*)d_in[3];
  const float* ks_b = (const float*)d_in[4];
  const float* vs_w = (const float*)d_in[5];
  const float* vs_b = (const float*)d_in[6];
  const float* ps_w = (const float*)d_in[7];
  const float* ps_b = (const float*)d_in[8];
  const float* qt_w = (const float*)d_in[9];
  const float* qt_b = (const float*)d_in[10];
  const float* kt_w = (const float*)d_in[11];
  const float* kt_b = (const float*)d_in[12];
  const float* vt_w = (const float*)d_in[13];
  const float* vt_b = (const float*)d_in[14];
  const float* pt_w = (const float*)d_in[15];
  const float* pt_b = (const float*)d_in[16];
  const float* g_s  = (const float*)d_in[17];
  const float* g_t  = (const float*)d_in[18];
  const int*   wnd  = (const int*)d_in[19];
  float* out = (float*)d_out;
  (void)ks_b; (void)kt_b;   // K biases appear only via wu (zero cross-terms cancel)

  // workspace carve (~136 MB)
  char* w = (char*)d_ws;
  short* Wb   = (short*)(w);                               // 4 MB: 8 weight slots
  float* ss_s = (float*)(w + (4L << 20));                  // 64 KB (zeroed group start)
  float* ss_t = (float*)(w + (4L << 20) + (64 << 10));     // 64 KB
  float* rsum = (float*)(w + (4L << 20) + (128 << 10));    // 64 KB
  float* us   = (float*)(w + (4L << 20) + (192 << 10));    // 64 KB
  float* ut   = (float*)(w + (4L << 20) + (256 << 10));    // 64 KB (zeroed group end)
  float* bt_s = (float*)(w + (4L << 20) + (320 << 10));    // 2 KB folded bias
  float* bt_t = (float*)(w + (4L << 20) + (324 << 10));    // 2 KB
  float* wus  = (float*)(w + (4L << 20) + (328 << 10));    // 2 KB u-weights
  float* wut  = (float*)(w + (4L << 20) + (332 << 10));    // 2 KB
  short* WF   = (short*)(w + (4L << 20) + (512 << 10));    // 2 MB: Wpv_s|Wpv_t|Mqk_s|Mqk_t
  short* Wpv  = WF;
  short* Mqk  = WF + 2 * 262144;
  short* hb   = (short*)(w + (8L << 20));                  // 16 MB: [16384][512] bf16 x^T
  short* Tb   = (short*)(w + (24L << 20));                 // 16 MB: [16384][512] T = M.h
  short* xb   = (short*)(w + (40L << 20));                 // 16 MB: [512][16384] bf16 x
  short* oT   = (short*)(w + (56L << 20));                 // 16 MB: [16384][512] h~
  short* h2   = (short*)(w + (72L << 20));                 // 16 MB: [16384][512]
  short* S    = (short*)(w + (88L << 20));                 // 32 MB: [16][1024][1024]
  (void)in_sizes; (void)n_in; (void)out_size; (void)ws_size;

  const float scale = 0.04419417382415922f;                // 512^-0.5

  setup_all<<<9024, 256, 0, stream>>>(
      qs_w, ks_w, vs_w, ps_w, qt_w, kt_w, vt_w, pt_w, g_s, g_t, Wb, ss_s,
      qs_b, vs_b, ps_b, qt_b, vt_b, pt_b, bt_s, bt_t, wus, wut);
  // Merged weight folds (z slot tables): z0 Wpv_s=ps.vs_g, z1 Wpv_t=pt.vt_g,
  // z2 Mqk_s=qs_g^T.ks_g, z3 Mqk_t=qt_g^T.kt_g
  gemm_nt<short, 0, 0, 0, 0, 128, 1, 64, 0><<<dim3(4, 4, 4), 256, 0, stream>>>(
      Wb, Wb, WF, nullptr, nullptr, nullptr, nullptr, nullptr, nullptr,
      nullptr, nullptr, 512, 512, 512, 512, 0, 0, 262144L, 0, 1.f);

  // ---------------- spatial ----------------
  txp_sumsq<<<dim3(256, 8, 1), 256, 0, stream>>>(x, hb, xb, ss_s, wus, us);
  // T[n][a] = hb[n,:] . Mqk_s[a,:]
  gemm_nt<short, 0, 0, 0, 0, 128, 0, 64, 1><<<dim3(128, 4, 1), 256, 0, stream>>>(
      hb, Mqk, Tb, nullptr, nullptr, nullptr, nullptr, nullptr, nullptr,
      nullptr, nullptr, 512, 512, 512, 512, 0, 0, 0, 0, 1.f);
  // expS'[t][l][m] = exp(scale*rms_m*(rms_l*(hb_l.T_m)+us_m))*rms_m ; rsum+=
  gemm_nt<short, 0, 4, 0, 1, 128, 0, 64, 1><<<dim3(8, 8, 16), 256, 0, stream>>>(
      hb, Tb, S, nullptr, ss_s, us, rsum, nullptr, nullptr, nullptr, nullptr,
      512, 512, 512, 1024,
      1024L * 512, 1024L * 512, 1024L * 1024, 1024, scale);
  // h~[n][c] = (1/rsum) * sum_m expS'[l,m] * xb[c,m]
  gemm_nt<short, 0, 3, 0, 0, 128, 0, 64, 1><<<dim3(8, 4, 16), 256, 0, stream>>>(
      S, xb, oT, nullptr, rsum, nullptr, nullptr, nullptr, nullptr,
      nullptr, nullptr, 1024, 1024, 16384, 512,
      1024L * 1024, 1024L, 1024L * 512, 1024, 1.f);
  // h2[n][c] = bf16( hb[n][c] + bt_s[c] + (oT.Wpv_s^T)[n][c] );
  //   ss_t += val^2 ; ut += val*wut[c]
  gemm_nt<short, 2, 0, 2, 3, 128, 0, 64, 1><<<dim3(128, 4, 1), 256, 0, stream>>>(
      oT, Wpv, h2, bt_s, nullptr, nullptr, ss_t, ut, wut, nullptr, hb,
      512, 512, 512, 512, 0, 0, 0, 1024, 1.f);

  // ---------------- temporal ----------------
  // Tt[n][a] = h2[n,:] . Mqk_t[a,:]
  gemm_nt<short, 0, 0, 0, 0, 128, 0, 64, 1><<<dim3(128, 4, 1), 256, 0, stream>>>(
      h2, Mqk + 262144, Tb, nullptr, nullptr, nullptr, nullptr, nullptr,
      nullptr, nullptr, nullptr, 512, 512, 512, 512, 0, 0, 0, 0, 1.f);
  temporal_attn_v5<<<1024, 256, 0, stream>>>(h2, Tb, ss_t, ut, wnd, oT, scale);
  // out[c,n] = h2[n][c] + bt_t[c] + Wpv_t[c,:] . h~[n,:]   (fp32, c-major)
  gemm_nt<float, 1, 0, 3, 0, 128, 0, 64, 1><<<dim3(4, 128, 1), 256, 0, stream>>>(
      Wpv + 262144, oT, out, bt_t, nullptr, nullptr, nullptr, nullptr,
      nullptr, nullptr, h2, 512, 512, 512, 16384, 0, 0, 0, 0, 1.f);
}

// Round 5
// 300.522 us; speedup vs baseline: 1.0233x; 1.0026x over previous
//
#include <hip/hip_runtime.h>

// ---------------------------------------------------------------------------
// Types & helpers
// ---------------------------------------------------------------------------
typedef __attribute__((ext_vector_type(8))) short bf16x8;
typedef __attribute__((ext_vector_type(4))) float f32x4;

__device__ __forceinline__ short f2bf(float f) {
  union { float f; unsigned u; } a; a.f = f;
  unsigned r = a.u + 0x7fffu + ((a.u >> 16) & 1u);   // RNE
  return (short)(r >> 16);
}
__device__ __forceinline__ float bf2f(short s) {
  union { unsigned u; float f; } a;
  a.u = ((unsigned)(unsigned short)s) << 16; return a.f;
}
__device__ __forceinline__ float blo(unsigned u) { union { unsigned u; float f; } a; a.u = u << 16; return a.f; }
__device__ __forceinline__ float bhi(unsigned u) { union { unsigned u; float f; } a; a.u = u & 0xffff0000u; return a.f; }
__device__ __forceinline__ unsigned packbf(float lo, float hi) {
  return (unsigned)(unsigned short)f2bf(lo) | ((unsigned)(unsigned short)f2bf(hi) << 16);
}
__device__ __forceinline__ void ldscp16(const void* g, void* l) {
  __builtin_amdgcn_global_load_lds((const __attribute__((address_space(1))) void*)g,
                                   (__attribute__((address_space(3))) void*)l, 16, 0, 0);
}
__device__ __forceinline__ void stv(float* p, float v) { *p = v; }
__device__ __forceinline__ void stv(short* p, float v) { *p = f2bf(v); }

// ---------------------------------------------------------------------------
// Merged setup. Blocks:
//  [0,8192)      cvt_w: slots 0 qs^T_g,1 ks^T_g,2 vs^T_g,3 ps,4 qt^T_g,
//                5 kt^T_g,6 vt^T_g,7 pt  (q/k/v transposed [c_in][c_out],
//                gamma folded on c_in; needed by the fold GEMMs)
//  [8192,8512)   zero 320 KB (ss_s|ss_t|rsum|us|ut)
//  [8512,9024)   row-folds, 4 waves/block, row b = (bid-8512)*4+wave:
//     b<512   : bt_s[b]   = ps_w[b,:].vs_b + ps_b[b]
//     b<1024  : bt_t[...] = pt_w.vt_b + pt_b
//     b<1536  : wus[c]    = g_s[c] * sum_o ks_w[o][c]*qs_b[o]   (u-vector wt)
//     b<2048  : wut[c]    = g_t[c] * sum_o kt_w[o][c]*qt_b[o]
// ---------------------------------------------------------------------------
__global__ __launch_bounds__(256) void setup_all(
    const float* __restrict__ w0, const float* __restrict__ w1,
    const float* __restrict__ w2, const float* __restrict__ w3,
    const float* __restrict__ w4, const float* __restrict__ w5,
    const float* __restrict__ w6, const float* __restrict__ w7,
    const float* __restrict__ g_s, const float* __restrict__ g_t,
    short* __restrict__ Wb, float* __restrict__ zs,
    const float* __restrict__ qs_b, const float* __restrict__ vs_b,
    const float* __restrict__ ps_b, const float* __restrict__ qt_b,
    const float* __restrict__ vt_b, const float* __restrict__ pt_b,
    float* __restrict__ bt_s, float* __restrict__ bt_t,
    float* __restrict__ wus, float* __restrict__ wut) {
  const int bid = blockIdx.x, tid = threadIdx.x;
  if (bid < 8192) {                                  // ---- cvt_w ----
    int idx = bid * 256 + tid;
    const float* ws[8] = {w0, w1, w2, w3, w4, w5, w6, w7};
    int wi = idx >> 18, loc = idx & 262143;
    int r = loc >> 9, q = loc & 511;
    float v, g;
    if (wi == 3 || wi == 7) { v = ws[wi][loc]; g = 1.f; }
    else {                                           // transposed, gamma on c_in=r
      v = ws[wi][q * 512 + r];
      g = (wi <= 2) ? g_s[r] : g_t[r];
    }
    Wb[idx] = f2bf(v * g);
  } else if (bid < 8512) {                           // ---- zero 320 KB ----
    zs[(bid - 8192) * 256 + tid] = 0.f;
  } else {                                           // ---- row folds ----
    const int w = tid >> 6, lane = tid & 63;
    const int b = (bid - 8512) * 4 + w;              // [0,2048)
    float s = 0.f;
    if (b < 1024) {                                  // bt = p_w.v_b + p_b
      const bool sp = b < 512;
      const float* W = sp ? w3 : w7;                 // ps_w : pt_w
      const float* vb = sp ? vs_b : vt_b;
      const int r = b & 511;
#pragma unroll
      for (int c = lane; c < 512; c += 64) s += W[r * 512 + c] * vb[c];
#pragma unroll
      for (int off = 32; off > 0; off >>= 1) s += __shfl_xor(s, off);
      if (lane == 0) (sp ? bt_s : bt_t)[r] = s + (sp ? ps_b : pt_b)[r];
    } else {                                         // wu = g * K_w^T.q_b
      const bool sp = b < 1536;
      const float* W = sp ? w1 : w5;                 // ks_w : kt_w
      const float* qb = sp ? qs_b : qt_b;
      const int c = b & 511;
#pragma unroll
      for (int o = lane; o < 512; o += 64) s += W[o * 512 + c] * qb[o];
#pragma unroll
      for (int off = 32; off > 0; off >>= 1) s += __shfl_xor(s, off);
      if (lane == 0)
        (sp ? wus : wut)[c] = s * (sp ? g_s[c] : g_t[c]);
    }
  }
}

// ---------------------------------------------------------------------------
// Transpose + sum-of-squares + u-dot (spatial). src [512][16384] fp32 ->
// dst [16384][512] bf16 (x^T), xb [512][16384] bf16 (straight cast),
// ss[n] += sum_c src[c][n]^2 ; us[n] += sum_c wu[c]*src[c][n].
// ---------------------------------------------------------------------------
__global__ __launch_bounds__(256) void txp_sumsq(
    const float* __restrict__ src, short* __restrict__ dst,
    short* __restrict__ xb, float* __restrict__ ss,
    const float* __restrict__ wu, float* __restrict__ us) {
  constexpr long N = 16384;
  __shared__ short T[64][66];
  __shared__ float part[16][16][4];
  __shared__ float part2[16][16][4];
  const int tid = threadIdx.x;
  const long n0 = (long)blockIdx.x * 64;
  const int c0 = blockIdx.y * 64;
  const int n4 = (tid & 15) * 4;
  float s0 = 0.f, s1 = 0.f, s2 = 0.f, s3 = 0.f;
  float u0 = 0.f, u1 = 0.f, u2 = 0.f, u3 = 0.f;
#pragma unroll
  for (int i = 0; i < 4; ++i) {
    int cl = i * 16 + (tid >> 4);
    float4 v = *(const float4*)&src[(long)(c0 + cl) * N + n0 + n4];
    float wc = wu[c0 + cl];
    s0 += v.x * v.x; s1 += v.y * v.y; s2 += v.z * v.z; s3 += v.w * v.w;
    u0 += wc * v.x; u1 += wc * v.y; u2 += wc * v.z; u3 += wc * v.w;
    short e0 = f2bf(v.x), e1 = f2bf(v.y), e2 = f2bf(v.z), e3 = f2bf(v.w);
    T[n4 + 0][cl] = e0; T[n4 + 1][cl] = e1;
    T[n4 + 2][cl] = e2; T[n4 + 3][cl] = e3;
    uint2 o;
    o.x = (unsigned)(unsigned short)e0 | ((unsigned)(unsigned short)e1 << 16);
    o.y = (unsigned)(unsigned short)e2 | ((unsigned)(unsigned short)e3 << 16);
    *(uint2*)&xb[(long)(c0 + cl) * N + n0 + n4] = o;
  }
  part[tid >> 4][tid & 15][0] = s0; part[tid >> 4][tid & 15][1] = s1;
  part[tid >> 4][tid & 15][2] = s2; part[tid >> 4][tid & 15][3] = s3;
  part2[tid >> 4][tid & 15][0] = u0; part2[tid >> 4][tid & 15][1] = u1;
  part2[tid >> 4][tid & 15][2] = u2; part2[tid >> 4][tid & 15][3] = u3;
  __syncthreads();
  if (tid < 64) {
    float s = 0.f, u = 0.f;
#pragma unroll
    for (int cg = 0; cg < 16; ++cg) {
      s += part[cg][tid >> 2][tid & 3];
      u += part2[cg][tid >> 2][tid & 3];
    }
    atomicAdd(&ss[n0 + tid], s);
    atomicAdd(&us[n0 + tid], u);
  }
#pragma unroll
  for (int p = 0; p < 4; ++p) {
    int nl = p * 16 + (tid >> 4);
    int cl = (tid & 15) * 4;
    uint2 o;
    o.x = (unsigned)(unsigned short)T[nl][cl] |
          ((unsigned)(unsigned short)T[nl][cl + 1] << 16);
    o.y = (unsigned)(unsigned short)T[nl][cl + 2] |
          ((unsigned)(unsigned short)T[nl][cl + 3] << 16);
    *(uint2*)&dst[(n0 + nl) * 512 + c0 + cl] = o;
  }
}

// ---------------------------------------------------------------------------
// Generic NT GEMM: D[i,j] = f( scale * sum_k A[i,k]*B[j,k] ) (+bias,+resid)
// SCALE_MODE: 0 none; 1 row-rms; 2 col-rms; 3 row-recip (softmax denom);
//             4 QK-fold+EXP: val = exp(scale*csc*(rms_row*acc + uvec[col])),
//               rowsum(atomic->rs) of unscaled exp, store val*csc.
// RESID_MODE: 0 none; 1 fp32 same-layout; 2 bf16 same-layout;
//             3 bf16 transposed (residb[j*512+i], uint2-gathered)
// EPI: 0 none; 1 EXP-rowsum (with SCALE4); 3 SUMSQ->rs + dot(wvec)->rs2
// FOLD: z indexes slot tables A{3,7,0,4} B{2,6,1,5} in Wb (weight folds).
// SWZ: bijective XCD chunk swizzle (m204) on the flattened block index.
//
// Round-5 structure: BM=64 tiles for all big GEMMs. Evidence chain:
//  - dbuf+counted-vmcnt NULL (r1/r2; T4 needs 8-phase regime, m230)
//  - launch_bounds 2->4 only helped the one GEMM whose grid had 4 blocks/CU
//    (r4); the 512-block grids are GRID-limited at 2/CU -> latency exposed.
//  - BM=64 (WR=1,WC=4,NW=2): 24 KB LDS, ~32 acc VGPR -> grids 1024-2048
//    blocks = 4-8 resident/CU; cross-block TLP is this structure's latency
//    hiding mechanism (m114).
//  NOTE: generalized wc = (waveid%WC)*(128/WC) — the old *64 was only
//  correct for WC<=2 (BM>=128).
// xor-swizzled LDS (chunk-xor by row & (BK/8-1)): 2-way max, free (m136).
// ---------------------------------------------------------------------------
template <typename OutT, int BIAS_MODE, int SCALE_MODE, int RESID_MODE, int EPI,
          int BM = 128, int FOLD = 0, int BK = 64, int SWZ = 0>
__global__ __launch_bounds__(256, (BM == 64) ? 5 : 4) void gemm_nt(
    const short* __restrict__ A, const short* __restrict__ B,
    OutT* __restrict__ D, const float* __restrict__ bias,
    const float* __restrict__ ssv, const float* __restrict__ uvec,
    float* __restrict__ rs, float* __restrict__ rs2,
    const float* __restrict__ wvec,
    const float* __restrict__ residf, const short* __restrict__ residb,
    int K, int lda, int ldb, int ldd,
    long aBatch, long bBatch, long dBatch, long sBatch, float scale) {
  constexpr int WR = (BM >= 64) ? BM / 64 : 1;       // wave rows
  constexpr int WC = 4 / WR;                         // wave cols
  constexpr int NW = (128 / WC) / 16;                // B-frags per wave (2/4/8)
  constexpr int WCS = 128 / WC;                      // wave col stride
  constexpr int CH = BK / 8;                         // 16B chunks per row
  constexpr int MSK = CH - 1;
  constexpr int RPR = 256 / CH;                      // rows staged per round
  __shared__ short As[BM * BK];
  __shared__ short Bs[128 * BK];
  const int tid = threadIdx.x;

  // ---- block-index decode (optionally XCD-chunk-swizzled, bijective) ----
  int lin = blockIdx.x + gridDim.x * (blockIdx.y + gridDim.y * blockIdx.z);
  if (SWZ) {
    const int nwg = gridDim.x * gridDim.y * gridDim.z;
    const int q = nwg >> 3, r = nwg & 7;
    const int xcd = lin & 7, idx = lin >> 3;
    lin = (xcd < r ? xcd * (q + 1) : r * (q + 1) + (xcd - r) * q) + idx;
  }
  const int bx = lin % gridDim.x;
  const int t1 = lin / gridDim.x;
  const int by = t1 % gridDim.y;
  const int bz = t1 / gridDim.y;

  const long i0 = (long)bx * BM;
  const long j0 = (long)by * 128;
  long aOff, bOff;
  if (FOLD) {
    aOff = 262144L * (bz < 2 ? 3 + 4 * bz : 4 * (bz - 2));
    bOff = 262144L * (bz < 2 ? 2 + 4 * bz : 1 + 4 * (bz - 2));
  } else {
    aOff = bz * aBatch; bOff = bz * bBatch;
  }
  const short* Ab = A + aOff + i0 * lda;
  const short* Bb = B + bOff + j0 * ldb;
  const int srow = tid / CH, scol = tid & MSK;
  const int lane = tid & 63;
  const int waveid = tid >> 6;
  const int wr = (waveid / WC) * 64;
  const int wc = (waveid % WC) * WCS;
  const int quad = lane >> 4, l15 = lane & 15;

  f32x4 acc[4][NW] = {};

  for (int k0 = 0; k0 < K; k0 += BK) {
    __syncthreads();
#pragma unroll
    for (int p = 0; p < BM / RPR; ++p) {
      int row = p * RPR + srow;
      int gc = (scol ^ (row & MSK)) << 3;
      ldscp16(Ab + (long)row * lda + k0 + gc, &As[p * 2048 + tid * 8]);
    }
#pragma unroll
    for (int p = 0; p < 128 / RPR; ++p) {
      int row = p * RPR + srow;
      int gc = (scol ^ (row & MSK)) << 3;
      ldscp16(Bb + (long)row * ldb + k0 + gc, &Bs[p * 2048 + tid * 8]);
    }
    __syncthreads();
#pragma unroll
    for (int kk = 0; kk < BK / 32; ++kk) {
      bf16x8 af[4], bfr[NW];
#pragma unroll
      for (int a = 0; a < 4; ++a) {
        int row = wr + a * 16 + l15;
        int g = kk * 4 + quad;
        af[a] = *(const bf16x8*)&As[row * BK + ((g ^ (row & MSK)) << 3)];
      }
#pragma unroll
      for (int b = 0; b < NW; ++b) {
        int row = wc + b * 16 + l15;
        int g = kk * 4 + quad;
        bfr[b] = *(const bf16x8*)&Bs[row * BK + ((g ^ (row & MSK)) << 3)];
      }
#pragma unroll
      for (int a = 0; a < 4; ++a)
#pragma unroll
        for (int b = 0; b < NW; ++b)
          acc[a][b] = __builtin_amdgcn_mfma_f32_16x16x32_bf16(af[a], bfr[b], acc[a][b], 0, 0, 0);
    }
  }

  const long Doff = bz * dBatch;
#pragma unroll
  for (int a = 0; a < 4; ++a) {
    const int rb = (int)i0 + wr + a * 16 + quad * 4;   // C/D: row = quad*4+reg
    float rsc[4];
    if (SCALE_MODE == 1 || SCALE_MODE == 4) {
#pragma unroll
      for (int r = 0; r < 4; ++r)
        rsc[r] = 22.627416997969522f /
                 fmaxf(sqrtf(ssv[bz * sBatch + rb + r]), 1e-12f);
    }
    if (SCALE_MODE == 3) {
#pragma unroll
      for (int r = 0; r < 4; ++r)
        rsc[r] = 1.f / ssv[bz * sBatch + rb + r];
    }
    float rp1[4] = {0.f, 0.f, 0.f, 0.f};
    float rp2[4] = {0.f, 0.f, 0.f, 0.f};
#pragma unroll
    for (int b = 0; b < NW; ++b) {
      const int cc = (int)j0 + wc + b * 16 + l15;      // C/D: col = lane&15
      float csc = 1.f, uu = 0.f, wv = 0.f;
      if (SCALE_MODE == 2 || SCALE_MODE == 4)
        csc = 22.627416997969522f /
              fmaxf(sqrtf(ssv[bz * sBatch + cc]), 1e-12f);
      if (SCALE_MODE == 4) uu = uvec[bz * sBatch + cc];
      if (EPI == 3) wv = wvec[cc];
      uint2 rtv;
      if (RESID_MODE == 3)
        rtv = *(const uint2*)&residb[(long)cc * 512 + rb];
#pragma unroll
      for (int r = 0; r < 4; ++r) {
        float val;
        if (SCALE_MODE == 4) {
          val = __expf(scale * csc * (rsc[r] * acc[a][b][r] + uu));
          rp1[r] += val;
          val *= csc;
        } else {
          val = acc[a][b][r] * scale;
          if (SCALE_MODE == 1 || SCALE_MODE == 3) val *= rsc[r];
          if (SCALE_MODE == 2) val *= csc;
        }
        if (BIAS_MODE == 1) val += bias[rb + r];
        if (BIAS_MODE == 2) val += bias[cc];
        const long off = Doff + (long)(rb + r) * ldd + cc;
        if (RESID_MODE == 1) val += residf[off];
        if (RESID_MODE == 2) val += bf2f(residb[off]);
        if (RESID_MODE == 3) val += bf2f(((const short*)&rtv)[r]);
        stv(D + off, val);
        if (EPI == 3) { rp1[r] += val * val; rp2[r] += val * wv; }
      }
    }
    if (EPI == 1 || EPI == 3) {
#pragma unroll
      for (int r = 0; r < 4; ++r) {
        float s = rp1[r];
#pragma unroll
        for (int off = 1; off < 16; off <<= 1) s += __shfl_xor(s, off);
        if (l15 == 0) atomicAdd(&rs[bz * sBatch + rb + r], s);
      }
      if (EPI == 3) {
#pragma unroll
        for (int r = 0; r < 4; ++r) {
          float s = rp2[r];
#pragma unroll
          for (int off = 1; off < 16; off <<= 1) s += __shfl_xor(s, off);
          if (l15 == 0) atomicAdd(&rs2[bz * sBatch + rb + r], s);
        }
      }
    }
  }
}

// ---------------------------------------------------------------------------
// Temporal attention v5 — QK-folded. h2: [16384][512] bf16, Tt = Mt.h2
// [16384][512] bf16. S[i,j] = scale*(rms_i*rms_j*(h2_i.Tt_j) + rms_j*ut_j).
// Block per pixel; V = rms-folded h2 (V projection folded into out-GEMM).
// ---------------------------------------------------------------------------
__global__ __launch_bounds__(256) void temporal_attn_v5(
    const short* __restrict__ h2, const short* __restrict__ Tt,
    const float* __restrict__ ss, const float* __restrict__ ut,
    const int* __restrict__ wndp, short* __restrict__ o, float scale) {
  constexpr int RS = 520;                            // 512 + 8 pad
  __shared__ short hq[16 * RS];
  __shared__ short tk[16 * RS];
  __shared__ float Plds[16][17];
  const int tid = threadIdx.x;
  const int w = tid >> 6, lane = tid & 63;
  const int hw = blockIdx.x;
  const int wnd = *wndp;

#pragma unroll
  for (int i = 0; i < 8; ++i) {
    int ci = w * 8 + i;                              // 32 rows: 0..15 h2, 16..31 Tt
    int t = ci & 15;
    const short* src = (ci < 16) ? h2 : Tt;
    short* dst = (ci < 16) ? hq : tk;
    ldscp16(src + (long)(t * 1024 + hw) * 512 + lane * 8,
            dst + t * RS + lane * 8);
  }
  const int c0 = lane * 8;
  uint4 vch[16];
#pragma unroll
  for (int tp = 0; tp < 16; ++tp)
    vch[tp] = *(const uint4*)(h2 + (long)(tp * 1024 + hw) * 512 + c0);
  __syncthreads();

  if (w == 0) {
    const int quad = lane >> 4, m = lane & 15;
    f32x4 sacc = {};
#pragma unroll
    for (int s = 0; s < 16; ++s) {
      bf16x8 aq = *(const bf16x8*)&hq[m * RS + quad * 8 + s * 32];
      bf16x8 bk = *(const bf16x8*)&tk[m * RS + quad * 8 + s * 32];
      sacc = __builtin_amdgcn_mfma_f32_16x16x32_bf16(aq, bk, sacc, 0, 0, 0);
    }
    const float rmsj = 22.627416997969522f /
                       fmaxf(sqrtf(ss[m * 1024 + hw]), 1e-12f);
    const float uj = ut[m * 1024 + hw];
#pragma unroll
    for (int r = 0; r < 4; ++r) {
      const int i = quad * 4 + r;
      const int j = m;
      const float rmsi = 22.627416997969522f /
                         fmaxf(sqrtf(ss[i * 1024 + hw]), 1e-12f);
      const bool allowed = (j <= i) && (wnd <= 0 || (i - j) < wnd);
      float val = allowed ? scale * (rmsi * rmsj * sacc[r] + rmsj * uj) : -1e30f;
      float mx = val;
#pragma unroll
      for (int off = 1; off < 16; off <<= 1) mx = fmaxf(mx, __shfl_xor(mx, off));
      float e = allowed ? __expf(val - mx) : 0.f;
      float sum = e;
#pragma unroll
      for (int off = 1; off < 16; off <<= 1) sum += __shfl_xor(sum, off);
      Plds[i][j] = (e / sum) * rmsj;                 // rms_j folded into P (V-fold)
    }
  }
  __syncthreads();

#pragma unroll
  for (int r = 0; r < 4; ++r) {
    const int t = w * 4 + r;
    const int tlo = (wnd > 0 && t - wnd + 1 > 0) ? t - wnd + 1 : 0;
    float a0 = 0.f, a1 = 0.f, a2 = 0.f, a3 = 0.f,
          a4 = 0.f, a5 = 0.f, a6 = 0.f, a7 = 0.f;
#pragma unroll
    for (int tp = 0; tp < 16; ++tp) {
      const float p = (tp >= tlo && tp <= t) ? Plds[t][tp] : 0.f;
      const uint4 vv = vch[tp];
      a0 += p * blo(vv.x); a1 += p * bhi(vv.x);
      a2 += p * blo(vv.y); a3 += p * bhi(vv.y);
      a4 += p * blo(vv.z); a5 += p * bhi(vv.z);
      a6 += p * blo(vv.w); a7 += p * bhi(vv.w);
    }
    uint4 ov;
    ov.x = packbf(a0, a1); ov.y = packbf(a2, a3);
    ov.z = packbf(a4, a5); ov.w = packbf(a6, a7);
    *(uint4*)(o + (long)(t * 1024 + hw) * 512 + c0) = ov;
  }
}

// ---------------------------------------------------------------------------
// Launch
// ---------------------------------------------------------------------------
extern "C" void kernel_launch(void* const* d_in, const int* in_sizes, int n_in,
                              void* d_out, int out_size, void* d_ws, size_t ws_size,
                              hipStream_t stream) {
  const float* x    = (const float*)d_in[0];
  const float* qs_w = (const float*)d_in[1];
  const float* qs_b = (const float*)d_in[2];
  const float* ks_w = (const float*)d_in[3];
  const float* ks_b = (const float*)d_in[4];
  const float* vs_w = (const float*)d_in[5];
  const float* vs_b = (const float*)d_in[6];
  const float* ps_w = (const float*)d_in[7];
  const float* ps_b = (const float*)d_in[8];
  const float* qt_w = (const float*)d_in[9];
  const float* qt_b = (const float*)d_in[10];
  const float* kt_w = (const float*)d_in[11];
  const float* kt_b = (const float*)d_in[12];
  const float* vt_w = (const float*)d_in[13];
  const float* vt_b = (const float*)d_in[14];
  const float* pt_w = (const float*)d_in[15];
  const float* pt_b = (const float*)d_in[16];
  const float* g_s  = (const float*)d_in[17];
  const float* g_t  = (const float*)d_in[18];
  const int*   wnd  = (const int*)d_in[19];
  float* out = (float*)d_out;
  (void)ks_b; (void)kt_b;   // K biases appear only via wu (zero cross-terms cancel)

  // workspace carve (~136 MB)
  char* w = (char*)d_ws;
  short* Wb   = (short*)(w);                               // 4 MB: 8 weight slots
  float* ss_s = (float*)(w + (4L << 20));                  // 64 KB (zeroed group start)
  float* ss_t = (float*)(w + (4L << 20) + (64 << 10));     // 64 KB
  float* rsum = (float*)(w + (4L << 20) + (128 << 10));    // 64 KB
  float* us   = (float*)(w + (4L << 20) + (192 << 10));    // 64 KB
  float* ut   = (float*)(w + (4L << 20) + (256 << 10));    // 64 KB (zeroed group end)
  float* bt_s = (float*)(w + (4L << 20) + (320 << 10));    // 2 KB folded bias
  float* bt_t = (float*)(w + (4L << 20) + (324 << 10));    // 2 KB
  float* wus  = (float*)(w + (4L << 20) + (328 << 10));    // 2 KB u-weights
  float* wut  = (float*)(w + (4L << 20) + (332 << 10));    // 2 KB
  short* WF   = (short*)(w + (4L << 20) + (512 << 10));    // 2 MB: Wpv_s|Wpv_t|Mqk_s|Mqk_t
  short* Wpv  = WF;
  short* Mqk  = WF + 2 * 262144;
  short* hb   = (short*)(w + (8L << 20));                  // 16 MB: [16384][512] bf16 x^T
  short* Tb   = (short*)(w + (24L << 20));                 // 16 MB: [16384][512] T = M.h
  short* xb   = (short*)(w + (40L << 20));                 // 16 MB: [512][16384] bf16 x
  short* oT   = (short*)(w + (56L << 20));                 // 16 MB: [16384][512] h~
  short* h2   = (short*)(w + (72L << 20));                 // 16 MB: [16384][512]
  short* S    = (short*)(w + (88L << 20));                 // 32 MB: [16][1024][1024]
  (void)in_sizes; (void)n_in; (void)out_size; (void)ws_size;

  const float scale = 0.04419417382415922f;                // 512^-0.5

  setup_all<<<9024, 256, 0, stream>>>(
      qs_w, ks_w, vs_w, ps_w, qt_w, kt_w, vt_w, pt_w, g_s, g_t, Wb, ss_s,
      qs_b, vs_b, ps_b, qt_b, vt_b, pt_b, bt_s, bt_t, wus, wut);
  // Merged weight folds (z slot tables): z0 Wpv_s=ps.vs_g, z1 Wpv_t=pt.vt_g,
  // z2 Mqk_s=qs_g^T.ks_g, z3 Mqk_t=qt_g^T.kt_g
  gemm_nt<short, 0, 0, 0, 0, 128, 1, 64, 0><<<dim3(4, 4, 4), 256, 0, stream>>>(
      Wb, Wb, WF, nullptr, nullptr, nullptr, nullptr, nullptr, nullptr,
      nullptr, nullptr, 512, 512, 512, 512, 0, 0, 262144L, 0, 1.f);

  // ---------------- spatial ----------------
  txp_sumsq<<<dim3(256, 8, 1), 256, 0, stream>>>(x, hb, xb, ss_s, wus, us);
  // T[n][a] = hb[n,:] . Mqk_s[a,:]   (BM=64: 1024 blocks = 4/CU)
  gemm_nt<short, 0, 0, 0, 0, 64, 0, 64, 1><<<dim3(256, 4, 1), 256, 0, stream>>>(
      hb, Mqk, Tb, nullptr, nullptr, nullptr, nullptr, nullptr, nullptr,
      nullptr, nullptr, 512, 512, 512, 512, 0, 0, 0, 0, 1.f);
  // expS'[t][l][m] = exp(scale*rms_m*(rms_l*(hb_l.T_m)+us_m))*rms_m ; rsum+=
  // (BM=64: 2048 blocks = up to 8/CU resident)
  gemm_nt<short, 0, 4, 0, 1, 64, 0, 64, 1><<<dim3(16, 8, 16), 256, 0, stream>>>(
      hb, Tb, S, nullptr, ss_s, us, rsum, nullptr, nullptr, nullptr, nullptr,
      512, 512, 512, 1024,
      1024L * 512, 1024L * 512, 1024L * 1024, 1024, scale);
  // h~[n][c] = (1/rsum) * sum_m expS'[l,m] * xb[c,m]   (BM=64: 1024 blocks)
  gemm_nt<short, 0, 3, 0, 0, 64, 0, 64, 1><<<dim3(16, 4, 16), 256, 0, stream>>>(
      S, xb, oT, nullptr, rsum, nullptr, nullptr, nullptr, nullptr,
      nullptr, nullptr, 1024, 1024, 16384, 512,
      1024L * 1024, 1024L, 1024L * 512, 1024, 1.f);
  // h2[n][c] = bf16( hb[n][c] + bt_s[c] + (oT.Wpv_s^T)[n][c] );
  //   ss_t += val^2 ; ut += val*wut[c]   (BM=64: 1024 blocks)
  gemm_nt<short, 2, 0, 2, 3, 64, 0, 64, 1><<<dim3(256, 4, 1), 256, 0, stream>>>(
      oT, Wpv, h2, bt_s, nullptr, nullptr, ss_t, ut, wut, nullptr, hb,
      512, 512, 512, 512, 0, 0, 0, 1024, 1.f);

  // ---------------- temporal ----------------
  // Tt[n][a] = h2[n,:] . Mqk_t[a,:]   (BM=64: 1024 blocks)
  gemm_nt<short, 0, 0, 0, 0, 64, 0, 64, 1><<<dim3(256, 4, 1), 256, 0, stream>>>(
      h2, Mqk + 262144, Tb, nullptr, nullptr, nullptr, nullptr, nullptr,
      nullptr, nullptr, nullptr, 512, 512, 512, 512, 0, 0, 0, 0, 1.f);
  temporal_attn_v5<<<1024, 256, 0, stream>>>(h2, Tb, ss_t, ut, wnd, oT, scale);
  // out[c,n] = h2[n][c] + bt_t[c] + Wpv_t[c,:] . h~[n,:]   (fp32, c-major)
  // (BM=64: 1024 blocks)
  gemm_nt<float, 1, 0, 3, 0, 64, 0, 64, 1><<<dim3(8, 128, 1), 256, 0, stream>>>(
      Wpv + 262144, oT, out, bt_t, nullptr, nullptr, nullptr, nullptr,
      nullptr, nullptr, h2, 512, 512, 512, 16384, 0, 0, 0, 0, 1.f);
}